// Round 6
// baseline (362.461 us; speedup 1.0000x reference)
//
#include <hip/hip_runtime.h>
#include <hip/hip_bf16.h>
#include <stdint.h>

#define NTOK 32768
#define HD 1024
#define FD 512
#define NEXP 8
#define TAU 0.05f
#define TAU2 4e-4f

typedef __attribute__((ext_vector_type(8))) short short8;
typedef __attribute__((ext_vector_type(4))) float f32x4;

__device__ __forceinline__ short f2bh(float f) {
  uint32_t u = __float_as_uint(f);
  return (short)((u + 0x7fffu + ((u >> 16) & 1u)) >> 16);
}
__device__ __forceinline__ float bh2f(short h) {
  return __uint_as_float(((uint32_t)(uint16_t)h) << 16);
}

__device__ __forceinline__ void gl16(void* lds, const void* g) {
  __builtin_amdgcn_global_load_lds(
      (const __attribute__((address_space(1))) void*)g,
      (__attribute__((address_space(3))) void*)lds, 16, 0, 0);
}

// ---------------------------------------------------------------------------
__global__ __launch_bounds__(256) void k_convert(const float* __restrict__ x,
                                                 short* __restrict__ xbf) {
  size_t i = ((size_t)blockIdx.x * 256 + threadIdx.x) * 8;
  f32x4 v0 = *(const f32x4*)(x + i);
  f32x4 v1 = *(const f32x4*)(x + i + 4);
  short8 o;
#pragma unroll
  for (int q = 0; q < 4; ++q) { o[q] = f2bh(v0[q]); o[4 + q] = f2bh(v1[q]); }
  *(short8*)(xbf + i) = o;
}

// ---------------------------------------------------------------------------
__global__ __launch_bounds__(256) void k_transpose(
    const float* __restrict__ src, short* __restrict__ dst, int rows, int cols) {
  __shared__ float tile[32][33];
  size_t msz = (size_t)rows * cols;
  src += (size_t)blockIdx.z * msz;
  dst += (size_t)blockIdx.z * msz;
  int c0 = blockIdx.x * 32, r0 = blockIdx.y * 32;
  int tx = threadIdx.x & 31, ty = threadIdx.x >> 5;
#pragma unroll
  for (int i = 0; i < 32; i += 8)
    tile[ty + i][tx] = src[(size_t)(r0 + ty + i) * cols + c0 + tx];
  __syncthreads();
#pragma unroll
  for (int i = 0; i < 32; i += 8)
    dst[(size_t)(c0 + ty + i) * rows + r0 + tx] = f2bh(tile[tx][ty + i]);
}

// ---------------------------------------------------------------------------
__global__ __launch_bounds__(256) void k_transpose_split(
    const float* __restrict__ src, short* __restrict__ dstH,
    short* __restrict__ dstL, int rows, int cols) {
  __shared__ float tile[32][33];
  int c0 = blockIdx.x * 32, r0 = blockIdx.y * 32;
  int tx = threadIdx.x & 31, ty = threadIdx.x >> 5;
#pragma unroll
  for (int i = 0; i < 32; i += 8)
    tile[ty + i][tx] = src[(size_t)(r0 + ty + i) * cols + c0 + tx];
  __syncthreads();
#pragma unroll
  for (int i = 0; i < 32; i += 8) {
    float v = tile[tx][ty + i];
    short h = f2bh(v);
    size_t di = (size_t)(c0 + ty + i) * rows + r0 + tx;
    dstH[di] = h;
    dstL[di] = f2bh(v - bh2f(h));
  }
}

// ---------------------------------------------------------------------------
// GEMM1: 128x128 tile, BK=32, 4 waves, double-buffered prefetch K-loop
// (T3 minimum 2-phase). Fused MFMA logits epilogue -> part[t][by*8+e].
// ---------------------------------------------------------------------------
template <bool ABF>
__global__ __launch_bounds__(256) void k_gemm1(
    const short* __restrict__ xbf, const float* __restrict__ xf,
    const short* __restrict__ W1T, const float* __restrict__ b1,
    const float* __restrict__ W2, float* __restrict__ part) {
  __shared__ __align__(16) char smem[39168];
  // K-loop layout: A0 [0,8K) A1 [8K,16K) B0 [16K,24K) B1 [24K,32K)

  const int tid = threadIdx.x;
  const int lane = tid & 63, wave = tid >> 6;
  const int wr = wave >> 1, wc = wave & 1;
  const int fr = lane & 15, fg = lane >> 4;
  const int bx = ((blockIdx.x & 7) << 5) | (blockIdx.x >> 3);  // T1, 256=8*32
  const int m0 = bx * 128, n0 = blockIdx.y * 128;
  const int by = blockIdx.y;

  const int off0 = wave * 1024 + lane * 16;  // bytes within 8KB tile
  const int r0 = off0 >> 6, c0 = (off0 & 63) >> 1;
  const int r1 = r0 + 64, c1 = c0;
  const short* b0p = W1T + (size_t)(n0 + r0) * HD + c0;
  const short* b1p = W1T + (size_t)(n0 + r1) * HD + c1;

  const short* a0p = nullptr; const short* a1p = nullptr;
  const float* aF = nullptr;
  int ar = 0, ah = 0;
  if constexpr (ABF) {
    a0p = xbf + (size_t)(m0 + r0) * HD + c0;
    a1p = xbf + (size_t)(m0 + r1) * HD + c1;
  } else {
    ar = tid >> 1; ah = tid & 1;
    aF = xf + (size_t)(m0 + ar) * HD + ah * 16;
  }

  f32x4 acc[4][4];
#pragma unroll
  for (int i = 0; i < 4; ++i)
#pragma unroll
    for (int j = 0; j < 4; ++j) acc[i][j] = (f32x4){0.f, 0.f, 0.f, 0.f};

  auto STAGE = [&](int kt, int b) {
    int k0 = kt * 32;
    gl16(smem + 16384 + b * 8192 + wave * 1024, b0p + k0);
    gl16(smem + 16384 + b * 8192 + 4096 + wave * 1024, b1p + k0);
    if constexpr (ABF) {
      gl16(smem + b * 8192 + wave * 1024, a0p + k0);
      gl16(smem + b * 8192 + 4096 + wave * 1024, a1p + k0);
    } else {
      f32x4 u0 = *(const f32x4*)(aF + k0);
      f32x4 u1 = *(const f32x4*)(aF + k0 + 4);
      f32x4 u2 = *(const f32x4*)(aF + k0 + 8);
      f32x4 u3 = *(const f32x4*)(aF + k0 + 12);
      short8 s0, s1;
#pragma unroll
      for (int q = 0; q < 4; ++q) {
        s0[q] = f2bh(u0[q]); s0[4 + q] = f2bh(u1[q]);
        s1[q] = f2bh(u2[q]); s1[4 + q] = f2bh(u3[q]);
      }
      short* As = (short*)(smem + b * 8192);
      *(short8*)(As + ar * 32 + ah * 16) = s0;
      *(short8*)(As + ar * 32 + ah * 16 + 8) = s1;
    }
  };
  auto COMPUTE = [&](int b) {
    const short* As = (const short*)(smem + b * 8192);
    const short* Bs = (const short*)(smem + 16384 + b * 8192);
    short8 af[4], bf[4];
#pragma unroll
    for (int i = 0; i < 4; ++i) {
      af[i] = *(const short8*)(As + (wr * 64 + i * 16 + fr) * 32 + fg * 8);
      bf[i] = *(const short8*)(Bs + (wc * 64 + i * 16 + fr) * 32 + fg * 8);
    }
#pragma unroll
    for (int i = 0; i < 4; ++i)
#pragma unroll
      for (int j = 0; j < 4; ++j)
        acc[i][j] = __builtin_amdgcn_mfma_f32_16x16x32_bf16(af[i], bf[j], acc[i][j], 0, 0, 0);
  };

  STAGE(0, 0);
  __syncthreads();
#pragma unroll 1
  for (int kt = 0; kt < 32; kt += 2) {
    if (kt + 1 < 32) STAGE(kt + 1, 1);
    COMPUTE(0);
    __syncthreads();
    if (kt + 2 < 32) STAGE(kt + 2, 0);
    COMPUTE(1);
    __syncthreads();
  }

  // Epilogue: relu(acc+b1) -> hbf [128][136] bf16 (one pass, quadrants tile
  // 128x128); logits via MFMA vs W2b [16][136] (cols 8..15 zero).
  short* hbf = (short*)smem;            // 34816 B
  short* W2b = (short*)(smem + 34816);  // 4352 B
  float b1j[4];
#pragma unroll
  for (int j = 0; j < 4; ++j) b1j[j] = b1[n0 + wc * 64 + j * 16 + fr];
  for (int q = tid; q < 2048; q += 256) {
    int col = q >> 7, k = q & 127;
    W2b[col * 136 + k] = (col < 8) ? f2bh(W2[(size_t)(n0 + k) * 8 + col]) : (short)0;
  }
#pragma unroll
  for (int i = 0; i < 4; ++i)
#pragma unroll
    for (int j = 0; j < 4; ++j) {
      int col = wc * 64 + j * 16 + fr;
#pragma unroll
      for (int q = 0; q < 4; ++q)
        hbf[(wr * 64 + i * 16 + fg * 4 + q) * 136 + col] =
            f2bh(fmaxf(acc[i][j][q] + b1j[j], 0.f));
    }
  __syncthreads();
#pragma unroll
  for (int rg = 0; rg < 2; ++rg) {
    int row16 = wave * 32 + rg * 16;
    f32x4 accl = (f32x4){0.f, 0.f, 0.f, 0.f};
#pragma unroll
    for (int kk = 0; kk < 4; ++kk) {
      short8 a = *(const short8*)(hbf + (row16 + fr) * 136 + kk * 32 + fg * 8);
      short8 b = *(const short8*)(W2b + fr * 136 + kk * 32 + fg * 8);
      accl = __builtin_amdgcn_mfma_f32_16x16x32_bf16(a, b, accl, 0, 0, 0);
    }
    if (fr < 8) {
      float* pp = part + (size_t)(m0 + row16 + fg * 4) * 32 + by * 8 + fr;
#pragma unroll
      for (int q = 0; q < 4; ++q) pp[(size_t)q * 32] = accl[q];
    }
  }
}

// ---------------------------------------------------------------------------
__global__ __launch_bounds__(256) void k_combine(
    const float* __restrict__ part, const float* __restrict__ b2,
    int* __restrict__ sel, int* __restrict__ flagged, int* __restrict__ nflag) {
  int t = blockIdx.x * 256 + threadIdx.x;
  const float* p = part + (size_t)t * 32;
  float lg[8];
#pragma unroll
  for (int e = 0; e < 8; ++e) lg[e] = p[e] + p[8 + e] + p[16 + e] + p[24 + e] + b2[e];
  int be = 0; float best = lg[0];
#pragma unroll
  for (int e = 1; e < 8; ++e) if (lg[e] > best) { best = lg[e]; be = e; }
  float second = -3.4e38f;
#pragma unroll
  for (int e = 0; e < 8; ++e) if (e != be && lg[e] > second) second = lg[e];
  sel[t] = be;
  if (best - second < TAU) {
    int ix = atomicAdd(nflag, 1);
    if (ix < NTOK) flagged[ix] = t;
  }
}

// ---------------------------------------------------------------------------
// Tier-A: bf16x3 re-GEMM of flagged tokens (128-tile, scalar f32 epilogue).
// ---------------------------------------------------------------------------
__global__ __launch_bounds__(256) void k_gemmR(
    const float* __restrict__ x, const short* __restrict__ W1hT,
    const short* __restrict__ W1lT, const float* __restrict__ b1,
    const float* __restrict__ W2, const int* __restrict__ flagged,
    const int* __restrict__ nflag, float* __restrict__ partR) {
  __shared__ __align__(16) char smem[37888];
  __shared__ int toks[128];
  short* Ah = (short*)smem;
  short* Al = (short*)(smem + 8192);

  int nf = *nflag; if (nf > NTOK) nf = NTOK;
  const int m0 = blockIdx.x * 128;
  if (m0 >= nf) return;
  const int tid = threadIdx.x;
  if (tid < 128) {
    int s = m0 + tid;
    toks[tid] = flagged[s < nf ? s : nf - 1];
  }
  __syncthreads();

  const int lane = tid & 63, wave = tid >> 6;
  const int wr = wave >> 1, wc = wave & 1;
  const int fr = lane & 15, fg = lane >> 4;
  const int n0 = blockIdx.y * 128;
  const int by = blockIdx.y;

  const int off0 = wave * 1024 + lane * 16;
  const int off1 = off0 + 4096;
  const int r0 = off0 >> 6, c0 = (off0 & 63) >> 1;
  const int r1 = off1 >> 6, c1 = (off1 & 63) >> 1;
  const short* bh0p = W1hT + (size_t)(n0 + r0) * HD + c0;
  const short* bh1p = W1hT + (size_t)(n0 + r1) * HD + c1;
  const short* bl0p = W1lT + (size_t)(n0 + r0) * HD + c0;
  const short* bl1p = W1lT + (size_t)(n0 + r1) * HD + c1;
  char* ldsBh0 = smem + 16384 + wave * 1024;
  char* ldsBh1 = smem + 16384 + wave * 1024 + 4096;
  char* ldsBl0 = smem + 24576 + wave * 1024;
  char* ldsBl1 = smem + 24576 + wave * 1024 + 4096;
  const int ar = tid >> 1, ah2 = tid & 1;
  const float* aF = x + (size_t)toks[ar] * HD + ah2 * 16;

  f32x4 acc[4][4];
#pragma unroll
  for (int i = 0; i < 4; ++i)
#pragma unroll
    for (int j = 0; j < 4; ++j) acc[i][j] = (f32x4){0.f, 0.f, 0.f, 0.f};

  for (int k0 = 0; k0 < HD; k0 += 32) {
    gl16(ldsBh0, bh0p + k0);
    gl16(ldsBh1, bh1p + k0);
    gl16(ldsBl0, bl0p + k0);
    gl16(ldsBl1, bl1p + k0);
    f32x4 u0 = *(const f32x4*)(aF + k0);
    f32x4 u1 = *(const f32x4*)(aF + k0 + 4);
    f32x4 u2 = *(const f32x4*)(aF + k0 + 8);
    f32x4 u3 = *(const f32x4*)(aF + k0 + 12);
    short8 sh0, sh1, sl0, sl1;
#pragma unroll
    for (int q = 0; q < 4; ++q) {
      { float f = u0[q]; short h = f2bh(f); sh0[q]     = h; sl0[q]     = f2bh(f - bh2f(h)); }
      { float f = u1[q]; short h = f2bh(f); sh0[4 + q] = h; sl0[4 + q] = f2bh(f - bh2f(h)); }
      { float f = u2[q]; short h = f2bh(f); sh1[q]     = h; sl1[q]     = f2bh(f - bh2f(h)); }
      { float f = u3[q]; short h = f2bh(f); sh1[4 + q] = h; sl1[4 + q] = f2bh(f - bh2f(h)); }
    }
    *(short8*)(Ah + ar * 32 + ah2 * 16)     = sh0;
    *(short8*)(Ah + ar * 32 + ah2 * 16 + 8) = sh1;
    *(short8*)(Al + ar * 32 + ah2 * 16)     = sl0;
    *(short8*)(Al + ar * 32 + ah2 * 16 + 8) = sl1;
    __syncthreads();
    short8 af[4], alf[4], bf[4], blf[4];
#pragma unroll
    for (int i = 0; i < 4; ++i) {
      int row = (wr * 64 + i * 16 + fr) * 32 + fg * 8;
      af[i]  = *(const short8*)(Ah + row);
      alf[i] = *(const short8*)(Al + row);
      int rowb = (wc * 64 + i * 16 + fr) * 32 + fg * 8;
      bf[i]  = *(const short8*)((short*)(smem + 16384) + rowb);
      blf[i] = *(const short8*)((short*)(smem + 24576) + rowb);
    }
#pragma unroll
    for (int i = 0; i < 4; ++i)
#pragma unroll
      for (int j = 0; j < 4; ++j) {
        acc[i][j] = __builtin_amdgcn_mfma_f32_16x16x32_bf16(af[i],  bf[j],  acc[i][j], 0, 0, 0);
        acc[i][j] = __builtin_amdgcn_mfma_f32_16x16x32_bf16(af[i],  blf[j], acc[i][j], 0, 0, 0);
        acc[i][j] = __builtin_amdgcn_mfma_f32_16x16x32_bf16(alf[i], bf[j],  acc[i][j], 0, 0, 0);
      }
    __syncthreads();
  }

  float* hl64 = (float*)smem;            // [64][129]
  float* W2c  = (float*)(smem + 33024);  // [128][8]
  *(f32x4*)(W2c + tid * 4) = *(const f32x4*)(W2 + (size_t)n0 * NEXP + tid * 4);
  float b1j[4];
#pragma unroll
  for (int j = 0; j < 4; ++j) b1j[j] = b1[n0 + wc * 64 + j * 16 + fr];

  for (int p = 0; p < 2; ++p) {
    if (wr == p) {
#pragma unroll
      for (int i = 0; i < 4; ++i)
#pragma unroll
        for (int j = 0; j < 4; ++j) {
          int col = wc * 64 + j * 16 + fr;
#pragma unroll
          for (int q = 0; q < 4; ++q)
            hl64[(i * 16 + fg * 4 + q) * 129 + col] = fmaxf(acc[i][j][q] + b1j[j], 0.f);
        }
    }
    __syncthreads();
    if (tid < 128) {
      int r2 = tid & 63, eh = tid >> 6;
      const float* hrow = hl64 + r2 * 129;
      const float* wcp = W2c + eh * 4;
      float s0 = 0.f, s1 = 0.f, s2 = 0.f, s3 = 0.f;
      for (int f = 0; f < 128; ++f) {
        float hv = hrow[f];
        s0 += hv * wcp[f * 8 + 0];
        s1 += hv * wcp[f * 8 + 1];
        s2 += hv * wcp[f * 8 + 2];
        s3 += hv * wcp[f * 8 + 3];
      }
      float* pp = partR + (size_t)(m0 + p * 64 + r2) * 32 + by * 8 + eh * 4;
      pp[0] = s0; pp[1] = s1; pp[2] = s2; pp[3] = s3;
    }
    __syncthreads();
  }
}

// ---------------------------------------------------------------------------
__global__ __launch_bounds__(256) void k_combineR(
    const float* __restrict__ partR, const float* __restrict__ b2,
    const int* __restrict__ flagged, const int* __restrict__ nflag,
    int* __restrict__ sel, int* __restrict__ flagged2, int* __restrict__ nflag2) {
  int nf = *nflag; if (nf > NTOK) nf = NTOK;
  int s = blockIdx.x * 256 + threadIdx.x;
  if (s >= nf) return;
  int t = flagged[s];
  const float* p = partR + (size_t)s * 32;
  float lg[8];
#pragma unroll
  for (int e = 0; e < 8; ++e) lg[e] = p[e] + p[8 + e] + p[16 + e] + p[24 + e] + b2[e];
  int be = 0; float best = lg[0];
#pragma unroll
  for (int e = 1; e < 8; ++e) if (lg[e] > best) { best = lg[e]; be = e; }
  float second = -3.4e38f;
#pragma unroll
  for (int e = 0; e < 8; ++e) if (e != be && lg[e] > second) second = lg[e];
  sel[t] = be;
  if (best - second < TAU2) {
    int ix = atomicAdd(nflag2, 1);
    if (ix < NTOK) flagged2[ix] = t;
  }
}

// ---------------------------------------------------------------------------
__global__ __launch_bounds__(256) void k_recomputeB(
    const float* __restrict__ x, const float* __restrict__ W1,
    const float* __restrict__ b1, const float* __restrict__ W2,
    const float* __restrict__ b2, const int* __restrict__ flagged2,
    const int* __restrict__ nflag2, int* __restrict__ sel) {
  __shared__ float xs[1024];
  __shared__ double hs[512];
  __shared__ double red[8][32];
  __shared__ double lgd[8];
  int nf = *nflag2; if (nf > NTOK) nf = NTOK;
  const int tid = threadIdx.x;
  for (int ti = blockIdx.x; ti < nf; ti += gridDim.x) {
    int t = flagged2[ti];
    __syncthreads();
    for (int q = tid; q < 1024; q += 256) xs[q] = x[(size_t)t * HD + q];
    __syncthreads();
    int f0 = tid * 2;
    double a0 = 0.0, a1 = 0.0;
    for (int h = 0; h < 1024; h += 4) {
      float2 w0 = *(const float2*)(W1 + (size_t)(h + 0) * FD + f0);
      float2 w1 = *(const float2*)(W1 + (size_t)(h + 1) * FD + f0);
      float2 w2 = *(const float2*)(W1 + (size_t)(h + 2) * FD + f0);
      float2 w3 = *(const float2*)(W1 + (size_t)(h + 3) * FD + f0);
      double x0 = (double)xs[h], x1 = (double)xs[h + 1];
      double x2 = (double)xs[h + 2], x3 = (double)xs[h + 3];
      a0 += x0 * (double)w0.x; a1 += x0 * (double)w0.y;
      a0 += x1 * (double)w1.x; a1 += x1 * (double)w1.y;
      a0 += x2 * (double)w2.x; a1 += x2 * (double)w2.y;
      a0 += x3 * (double)w3.x; a1 += x3 * (double)w3.y;
    }
    a0 += (double)b1[f0]; a1 += (double)b1[f0 + 1];
    hs[f0]     = a0 > 0.0 ? a0 : 0.0;
    hs[f0 + 1] = a1 > 0.0 ? a1 : 0.0;
    __syncthreads();
    {
      int e = tid >> 5, c = tid & 31;
      int fb = c * 16;
      double s = 0.0;
#pragma unroll
      for (int ff = 0; ff < 16; ++ff)
        s += hs[fb + ff] * (double)W2[(size_t)(fb + ff) * 8 + e];
      red[e][c] = s;
    }
    __syncthreads();
    if (tid < 8) {
      double s = 0.0;
#pragma unroll
      for (int c = 0; c < 32; ++c) s += red[tid][c];
      lgd[tid] = s + (double)b2[tid];
    }
    __syncthreads();
    if (tid == 0) {
      int be = 0; double best = lgd[0];
#pragma unroll
      for (int e = 1; e < 8; ++e) if (lgd[e] > best) { best = lgd[e]; be = e; }
      sel[t] = be;
    }
    __syncthreads();
  }
}

// ---------------------------------------------------------------------------
__global__ __launch_bounds__(256) void k_compact(
    const int* __restrict__ sel, int* __restrict__ cnt, int* __restrict__ list) {
  __shared__ int wcnt[4][8];
  __shared__ int woff[4][8];
  __shared__ int bbase[8];
  const int tid = threadIdx.x, lane = tid & 63, wave = tid >> 6;
  const int t = blockIdx.x * 256 + tid;
  const int e = sel[t];
  const unsigned long long ltmask = (1ull << lane) - 1ull;
  int rank = 0;
#pragma unroll
  for (int e2 = 0; e2 < 8; ++e2) {
    unsigned long long m = __ballot(e == e2);
    if (e2 == e) rank = __popcll(m & ltmask);
    if (lane == 0) wcnt[wave][e2] = __popcll(m);
  }
  __syncthreads();
  if (tid < 8) {
    int s0 = wcnt[0][tid], s1 = wcnt[1][tid], s2 = wcnt[2][tid], s3 = wcnt[3][tid];
    woff[0][tid] = 0; woff[1][tid] = s0; woff[2][tid] = s0 + s1; woff[3][tid] = s0 + s1 + s2;
    bbase[tid] = atomicAdd(&cnt[tid], s0 + s1 + s2 + s3);
  }
  __syncthreads();
  list[(size_t)e * NTOK + bbase[e] + woff[wave][e] + rank] = t;
}

__global__ void k_build_desc(const int* __restrict__ cnt, int* __restrict__ desc,
                             int* __restrict__ ntl) {
  if (threadIdx.x == 0 && blockIdx.x == 0) {
    int n = 0;
    for (int e = 0; e < 8; ++e) {
      int m = (cnt[e] + 127) >> 7;
      for (int i = 0; i < m; ++i) desc[n++] = (e << 16) | i;
    }
    *ntl = n;
  }
}

// ---------------------------------------------------------------------------
// GEMM2: 128x128 tile, BK=32, 4 waves, gathered A rows, prefetch-dbuf K-loop.
// ---------------------------------------------------------------------------
template <bool ABF>
__global__ __launch_bounds__(256) void k_gemm2(
    const short* __restrict__ xbf, const float* __restrict__ xf,
    const short* __restrict__ WexpT, const float* __restrict__ expert_b,
    const int* __restrict__ cnt, const int* __restrict__ list,
    const int* __restrict__ desc, const int* __restrict__ ntl,
    float* __restrict__ out) {
  __shared__ __align__(16) char smem[32768];
  __shared__ int toks[128];
  const int bx = (blockIdx.x % 8) * 33 + blockIdx.x / 8;  // T1 bijective, 264=8*33
  if (bx >= *ntl) return;
  int dsc = desc[bx];
  int e = dsc >> 16, mt = dsc & 0xffff;
  int ce = cnt[e];
  int mb = mt * 128;
  int rows = ce - mb; if (rows > 128) rows = 128;

  const int tid = threadIdx.x;
  if (tid < 128) {
    int idx = mb + tid;
    toks[tid] = list[(size_t)e * NTOK + (idx < ce ? idx : ce - 1)];
  }
  __syncthreads();

  const int lane = tid & 63, wave = tid >> 6;
  const int wr = wave >> 1, wc = wave & 1;
  const int fr = lane & 15, fg = lane >> 4;
  const int n0 = blockIdx.y * 128;

  const int off0 = wave * 1024 + lane * 16;
  const int r0 = off0 >> 6, c0 = (off0 & 63) >> 1;
  const int r1 = r0 + 64, c1 = c0;
  const size_t ebase = (size_t)e << 20;
  const short* b0p = WexpT + ebase + (size_t)(n0 + r0) * HD + c0;
  const short* b1p = WexpT + ebase + (size_t)(n0 + r1) * HD + c1;

  const short* a0p = nullptr; const short* a1p = nullptr;
  const float* aF = nullptr;
  int ar = 0, ah = 0;
  if constexpr (ABF) {
    a0p = xbf + (size_t)toks[r0] * HD + c0;
    a1p = xbf + (size_t)toks[r1] * HD + c1;
  } else {
    ar = tid >> 1; ah = tid & 1;
    aF = xf + (size_t)toks[ar] * HD + ah * 16;
  }

  f32x4 acc[4][4];
#pragma unroll
  for (int i = 0; i < 4; ++i)
#pragma unroll
    for (int j = 0; j < 4; ++j) acc[i][j] = (f32x4){0.f, 0.f, 0.f, 0.f};

  auto STAGE = [&](int kt, int b) {
    int k0 = kt * 32;
    gl16(smem + 16384 + b * 8192 + wave * 1024, b0p + k0);
    gl16(smem + 16384 + b * 8192 + 4096 + wave * 1024, b1p + k0);
    if constexpr (ABF) {
      gl16(smem + b * 8192 + wave * 1024, a0p + k0);
      gl16(smem + b * 8192 + 4096 + wave * 1024, a1p + k0);
    } else {
      f32x4 u0 = *(const f32x4*)(aF + k0);
      f32x4 u1 = *(const f32x4*)(aF + k0 + 4);
      f32x4 u2 = *(const f32x4*)(aF + k0 + 8);
      f32x4 u3 = *(const f32x4*)(aF + k0 + 12);
      short8 s0, s1;
#pragma unroll
      for (int q = 0; q < 4; ++q) {
        s0[q] = f2bh(u0[q]); s0[4 + q] = f2bh(u1[q]);
        s1[q] = f2bh(u2[q]); s1[4 + q] = f2bh(u3[q]);
      }
      short* As = (short*)(smem + b * 8192);
      *(short8*)(As + ar * 32 + ah * 16) = s0;
      *(short8*)(As + ar * 32 + ah * 16 + 8) = s1;
    }
  };
  auto COMPUTE = [&](int b) {
    const short* As = (const short*)(smem + b * 8192);
    const short* Bs = (const short*)(smem + 16384 + b * 8192);
    short8 af[4], bf[4];
#pragma unroll
    for (int i = 0; i < 4; ++i) {
      af[i] = *(const short8*)(As + (wr * 64 + i * 16 + fr) * 32 + fg * 8);
      bf[i] = *(const short8*)(Bs + (wc * 64 + i * 16 + fr) * 32 + fg * 8);
    }
#pragma unroll
    for (int i = 0; i < 4; ++i)
#pragma unroll
      for (int j = 0; j < 4; ++j)
        acc[i][j] = __builtin_amdgcn_mfma_f32_16x16x32_bf16(af[i], bf[j], acc[i][j], 0, 0, 0);
  };

  STAGE(0, 0);
  __syncthreads();
#pragma unroll 1
  for (int kt = 0; kt < 32; kt += 2) {
    if (kt + 1 < 32) STAGE(kt + 1, 1);
    COMPUTE(0);
    __syncthreads();
    if (kt + 2 < 32) STAGE(kt + 2, 0);
    COMPUTE(1);
    __syncthreads();
  }

  float ebv[4];
#pragma unroll
  for (int j = 0; j < 4; ++j) ebv[j] = expert_b[e * HD + n0 + wc * 64 + j * 16 + fr];
#pragma unroll
  for (int i = 0; i < 4; ++i)
#pragma unroll
    for (int j = 0; j < 4; ++j) {
      int col = n0 + wc * 64 + j * 16 + fr;
#pragma unroll
      for (int q = 0; q < 4; ++q) {
        int rr = wr * 64 + i * 16 + fg * 4 + q;
        if (rr < rows) out[(size_t)toks[rr] * HD + col] = acc[i][j][q] + ebv[j];
      }
    }
}

// ---------------------------------------------------------------------------
extern "C" void kernel_launch(void* const* d_in, const int* in_sizes, int n_in,
                              void* d_out, int out_size, void* d_ws, size_t ws_size,
                              hipStream_t stream) {
  const float* x  = (const float*)d_in[0];
  const float* W1 = (const float*)d_in[1];
  const float* b1 = (const float*)d_in[2];
  const float* W2 = (const float*)d_in[3];
  const float* b2 = (const float*)d_in[4];
  const float* eW = (const float*)d_in[5];
  const float* eb = (const float*)d_in[6];
  float* out = (float*)d_out;
  char* ws = (char*)d_ws;

  const size_t XBF_BYTES = (size_t)NTOK * HD * 2;  // 67,108,864
  size_t need_rest = 16777216ull + 1048576 + 4194304 + 131072 * 3 + 1048576 + 4096;
  bool big = ws_size >= XBF_BYTES + need_rest;

  size_t off = 0;
  short* xbf = nullptr;
  if (big) { xbf = (short*)ws; off += XBF_BYTES; }
  short* WexpT  = (short*)(ws + off); off += 16777216;
  short* W1T    = (short*)(ws + off); off += 1048576;
  float* part   = (float*)(ws + off); off += 4194304;   // also partR (tier-A)
  int* sel      = (int*)(ws + off); off += 131072;
  int* flagged  = (int*)(ws + off); off += 131072;
  int* flagged2 = (int*)(ws + off); off += 131072;
  int* list     = (int*)(ws + off); off += 1048576;     // also W1lT before compact
  int* cnt      = (int*)(ws + off); off += 32;
  int* nflag    = (int*)(ws + off); off += 4;
  int* ntl      = (int*)(ws + off); off += 4;
  int* nflag2   = (int*)(ws + off); off += 24;
  int* desc     = (int*)(ws + off); off += 1088;
  if (ws_size < off) return;

  short* W1lT = (short*)list;  // 1 MB, live until k_compact

  hipMemsetAsync(cnt, 0, 44, stream);  // cnt[8], nflag, ntl, nflag2

  dim3 b256(256);
  if (big) k_convert<<<dim3(16384), b256, 0, stream>>>(x, xbf);
  k_transpose_split<<<dim3(16, 32), b256, 0, stream>>>(W1, W1T, W1lT, 1024, 512);
  k_transpose<<<dim3(32, 32, 8), b256, 0, stream>>>(eW, WexpT, 1024, 1024);
  if (big)
    k_gemm1<true><<<dim3(256, 4), b256, 0, stream>>>(xbf, nullptr, W1T, b1, W2, part);
  else
    k_gemm1<false><<<dim3(256, 4), b256, 0, stream>>>(nullptr, x, W1T, b1, W2, part);
  k_combine<<<dim3(128), b256, 0, stream>>>(part, b2, sel, flagged, nflag);
  k_gemmR<<<dim3(256, 4), b256, 0, stream>>>(x, W1T, W1lT, b1, W2, flagged, nflag, part);
  k_combineR<<<dim3(128), b256, 0, stream>>>(part, b2, flagged, nflag, sel, flagged2, nflag2);
  k_recomputeB<<<dim3(128), b256, 0, stream>>>(x, W1, b1, W2, b2, flagged2, nflag2, sel);
  k_compact<<<dim3(128), b256, 0, stream>>>(sel, cnt, list);
  k_build_desc<<<dim3(1), dim3(64), 0, stream>>>(cnt, desc, ntl);
  if (big)
    k_gemm2<true><<<dim3(264, 8), b256, 0, stream>>>(xbf, nullptr, WexpT, eb, cnt, list, desc, ntl, out);
  else
    k_gemm2<false><<<dim3(264, 8), b256, 0, stream>>>(nullptr, x, WexpT, eb, cnt, list, desc, ntl, out);
}

// Round 7
// 362.020 us; speedup vs baseline: 1.0012x; 1.0012x over previous
//
#include <hip/hip_runtime.h>
#include <hip/hip_bf16.h>
#include <stdint.h>

#define NTOK 32768
#define HD 1024
#define FD 512
#define NEXP 8
#define TAU 0.05f
#define TAU2 4e-4f

typedef __attribute__((ext_vector_type(8))) short short8;
typedef __attribute__((ext_vector_type(4))) float f32x4;

__device__ __forceinline__ short f2bh(float f) {
  uint32_t u = __float_as_uint(f);
  return (short)((u + 0x7fffu + ((u >> 16) & 1u)) >> 16);
}
__device__ __forceinline__ float bh2f(short h) {
  return __uint_as_float(((uint32_t)(uint16_t)h) << 16);
}

__device__ __forceinline__ void gl16(void* lds, const void* g) {
  __builtin_amdgcn_global_load_lds(
      (const __attribute__((address_space(1))) void*)g,
      (__attribute__((address_space(3))) void*)lds, 16, 0, 0);
}

#define WAITBAR(N)                                              \
  do {                                                          \
    asm volatile("s_waitcnt vmcnt(" #N ")" ::: "memory");       \
    __builtin_amdgcn_s_barrier();                               \
    asm volatile("" ::: "memory");                              \
  } while (0)
#define BARO()                                                  \
  do {                                                          \
    asm volatile("" ::: "memory");                              \
    __builtin_amdgcn_s_barrier();                               \
    asm volatile("" ::: "memory");                              \
  } while (0)

// ---------------------------------------------------------------------------
__global__ __launch_bounds__(256) void k_convert(const float* __restrict__ x,
                                                 short* __restrict__ xbf) {
  size_t i = ((size_t)blockIdx.x * 256 + threadIdx.x) * 8;
  f32x4 v0 = *(const f32x4*)(x + i);
  f32x4 v1 = *(const f32x4*)(x + i + 4);
  short8 o;
#pragma unroll
  for (int q = 0; q < 4; ++q) { o[q] = f2bh(v0[q]); o[4 + q] = f2bh(v1[q]); }
  *(short8*)(xbf + i) = o;
}

// ---------------------------------------------------------------------------
__global__ __launch_bounds__(256) void k_transpose(
    const float* __restrict__ src, short* __restrict__ dst, int rows, int cols) {
  __shared__ float tile[32][33];
  size_t msz = (size_t)rows * cols;
  src += (size_t)blockIdx.z * msz;
  dst += (size_t)blockIdx.z * msz;
  int c0 = blockIdx.x * 32, r0 = blockIdx.y * 32;
  int tx = threadIdx.x & 31, ty = threadIdx.x >> 5;
#pragma unroll
  for (int i = 0; i < 32; i += 8)
    tile[ty + i][tx] = src[(size_t)(r0 + ty + i) * cols + c0 + tx];
  __syncthreads();
#pragma unroll
  for (int i = 0; i < 32; i += 8)
    dst[(size_t)(c0 + ty + i) * rows + r0 + tx] = f2bh(tile[tx][ty + i]);
}

// ---------------------------------------------------------------------------
__global__ __launch_bounds__(256) void k_transpose_split(
    const float* __restrict__ src, short* __restrict__ dstH,
    short* __restrict__ dstL, int rows, int cols) {
  __shared__ float tile[32][33];
  int c0 = blockIdx.x * 32, r0 = blockIdx.y * 32;
  int tx = threadIdx.x & 31, ty = threadIdx.x >> 5;
#pragma unroll
  for (int i = 0; i < 32; i += 8)
    tile[ty + i][tx] = src[(size_t)(r0 + ty + i) * cols + c0 + tx];
  __syncthreads();
#pragma unroll
  for (int i = 0; i < 32; i += 8) {
    float v = tile[tx][ty + i];
    short h = f2bh(v);
    size_t di = (size_t)(c0 + ty + i) * rows + r0 + tx;
    dstH[di] = h;
    dstL[di] = f2bh(v - bh2f(h));
  }
}

// ---------------------------------------------------------------------------
// GEMM1: 128x128 tile, BK=32, 4 waves. Counted-vmcnt dbuf pipeline (T4) +
// both-sides LDS swizzle (T2). Fused MFMA logits epilogue -> part[t][by*8+e].
// ---------------------------------------------------------------------------
template <bool ABF>
__global__ __launch_bounds__(256) void k_gemm1(
    const short* __restrict__ xbf, const float* __restrict__ xf,
    const short* __restrict__ W1T, const float* __restrict__ b1,
    const float* __restrict__ W2, float* __restrict__ part) {
  __shared__ __align__(16) char smem[39168];
  // A0 [0,8K) A1 [8K,16K) B0 [16K,24K) B1 [24K,32K)

  const int tid = threadIdx.x;
  const int lane = tid & 63, wave = tid >> 6;
  const int wr = wave >> 1, wc = wave & 1;
  const int fr = lane & 15, fg = lane >> 4;
  const int bx = ((blockIdx.x & 7) << 5) | (blockIdx.x >> 3);  // T1, 256=8*32
  const int m0 = bx * 128, n0 = blockIdx.y * 128;
  const int by = blockIdx.y;

  // swizzled staging: lane covers row r0 (+64 for 2nd call); LDS chunk (lane&3)
  // holds global chunk (lane&3)^((lane>>3)&3)  [slot = r*4 + (c ^ ((r>>1)&3))]
  const int r0 = wave * 16 + (lane >> 2);
  const int lsw = (((lane & 3) ^ ((lane >> 3) & 3)) << 3);
  const short* b0p = W1T + (size_t)(n0 + r0) * HD + lsw;
  const short* b1p = W1T + (size_t)(n0 + r0 + 64) * HD + lsw;

  const short* a0p = nullptr; const short* a1p = nullptr;
  const float* aF = nullptr;
  int ar = 0, ah = 0, p0e = 0, p1e = 0;
  if constexpr (ABF) {
    a0p = xbf + (size_t)(m0 + r0) * HD + lsw;
    a1p = xbf + (size_t)(m0 + r0 + 64) * HD + lsw;
  } else {
    ar = tid >> 1; ah = tid & 1;
    aF = xf + (size_t)(m0 + ar) * HD + ah * 16;
    int s = (ar >> 1) & 3;
    p0e = ((2 * ah) ^ s) << 3;
    p1e = p0e ^ 8;
  }

  f32x4 acc[4][4];
#pragma unroll
  for (int i = 0; i < 4; ++i)
#pragma unroll
    for (int j = 0; j < 4; ++j) acc[i][j] = (f32x4){0.f, 0.f, 0.f, 0.f};

  auto STAGE = [&](int kt, int b) {
    const int k0 = kt * 32;
    gl16(smem + 16384 + b * 8192 + wave * 1024, b0p + k0);
    gl16(smem + 16384 + b * 8192 + 4096 + wave * 1024, b1p + k0);
    if constexpr (ABF) {
      gl16(smem + b * 8192 + wave * 1024, a0p + k0);
      gl16(smem + b * 8192 + 4096 + wave * 1024, a1p + k0);
    } else {
      f32x4 u0 = *(const f32x4*)(aF + k0);
      f32x4 u1 = *(const f32x4*)(aF + k0 + 4);
      f32x4 u2 = *(const f32x4*)(aF + k0 + 8);
      f32x4 u3 = *(const f32x4*)(aF + k0 + 12);
      short8 s0, s1;
#pragma unroll
      for (int q = 0; q < 4; ++q) {
        s0[q] = f2bh(u0[q]); s0[4 + q] = f2bh(u1[q]);
        s1[q] = f2bh(u2[q]); s1[4 + q] = f2bh(u3[q]);
      }
      short* As = (short*)(smem + b * 8192);
      *(short8*)(As + ar * 32 + p0e) = s0;
      *(short8*)(As + ar * 32 + p1e) = s1;
    }
  };
  const int csw = (fr >> 1) & 3;
  auto COMPUTE = [&](int b) {
    const short* As = (const short*)(smem + b * 8192);
    const short* Bs = (const short*)(smem + 16384 + b * 8192);
    short8 af[4], bf4[4];
#pragma unroll
    for (int i = 0; i < 4; ++i) {
      af[i]  = *(const short8*)(As + (wr * 64 + i * 16 + fr) * 32 + ((fg ^ csw) << 3));
      bf4[i] = *(const short8*)(Bs + (wc * 64 + i * 16 + fr) * 32 + ((fg ^ csw) << 3));
    }
#pragma unroll
    for (int i = 0; i < 4; ++i)
#pragma unroll
      for (int j = 0; j < 4; ++j)
        acc[i][j] = __builtin_amdgcn_mfma_f32_16x16x32_bf16(af[i], bf4[j], acc[i][j], 0, 0, 0);
  };

  STAGE(0, 0);
  if constexpr (ABF) WAITBAR(0); else __syncthreads();
#pragma unroll 1
  for (int kt = 0; kt < 32; kt += 2) {
    STAGE(kt + 1, 1);
    if constexpr (ABF) WAITBAR(4); else __syncthreads();
    COMPUTE(0);
    if constexpr (ABF) BARO(); else __syncthreads();
    if (kt + 2 < 32) {
      STAGE(kt + 2, 0);
      if constexpr (ABF) WAITBAR(4); else __syncthreads();
    } else {
      if constexpr (ABF) WAITBAR(0); else __syncthreads();
    }
    COMPUTE(1);
    if constexpr (ABF) BARO(); else __syncthreads();
  }

  // Epilogue: relu(acc+b1) -> hbf [128][136] bf16; logits via MFMA vs
  // W2b [16][136] (cols 8..15 zero).
  short* hbf = (short*)smem;            // 34816 B
  short* W2b = (short*)(smem + 34816);  // 4352 B
  float b1j[4];
#pragma unroll
  for (int j = 0; j < 4; ++j) b1j[j] = b1[n0 + wc * 64 + j * 16 + fr];
  for (int q = tid; q < 2048; q += 256) {
    int col = q >> 7, k = q & 127;
    W2b[col * 136 + k] = (col < 8) ? f2bh(W2[(size_t)(n0 + k) * 8 + col]) : (short)0;
  }
#pragma unroll
  for (int i = 0; i < 4; ++i)
#pragma unroll
    for (int j = 0; j < 4; ++j) {
      int col = wc * 64 + j * 16 + fr;
#pragma unroll
      for (int q = 0; q < 4; ++q)
        hbf[(wr * 64 + i * 16 + fg * 4 + q) * 136 + col] =
            f2bh(fmaxf(acc[i][j][q] + b1j[j], 0.f));
    }
  __syncthreads();
#pragma unroll
  for (int rg = 0; rg < 2; ++rg) {
    int row16 = wave * 32 + rg * 16;
    f32x4 accl = (f32x4){0.f, 0.f, 0.f, 0.f};
#pragma unroll
    for (int kk = 0; kk < 4; ++kk) {
      short8 a = *(const short8*)(hbf + (row16 + fr) * 136 + kk * 32 + fg * 8);
      short8 b = *(const short8*)(W2b + fr * 136 + kk * 32 + fg * 8);
      accl = __builtin_amdgcn_mfma_f32_16x16x32_bf16(a, b, accl, 0, 0, 0);
    }
    if (fr < 8) {
      float* pp = part + (size_t)(m0 + row16 + fg * 4) * 32 + by * 8 + fr;
#pragma unroll
      for (int q = 0; q < 4; ++q) pp[(size_t)q * 32] = accl[q];
    }
  }
}

// ---------------------------------------------------------------------------
__global__ __launch_bounds__(256) void k_combine(
    const float* __restrict__ part, const float* __restrict__ b2,
    int* __restrict__ sel, int* __restrict__ flagged, int* __restrict__ nflag) {
  int t = blockIdx.x * 256 + threadIdx.x;
  const float* p = part + (size_t)t * 32;
  float lg[8];
#pragma unroll
  for (int e = 0; e < 8; ++e) lg[e] = p[e] + p[8 + e] + p[16 + e] + p[24 + e] + b2[e];
  int be = 0; float best = lg[0];
#pragma unroll
  for (int e = 1; e < 8; ++e) if (lg[e] > best) { best = lg[e]; be = e; }
  float second = -3.4e38f;
#pragma unroll
  for (int e = 0; e < 8; ++e) if (e != be && lg[e] > second) second = lg[e];
  sel[t] = be;
  if (best - second < TAU) {
    int ix = atomicAdd(nflag, 1);
    if (ix < NTOK) flagged[ix] = t;
  }
}

// ---------------------------------------------------------------------------
// Tier-A: bf16x3 re-GEMM of flagged tokens (unchanged structure).
// ---------------------------------------------------------------------------
__global__ __launch_bounds__(256) void k_gemmR(
    const float* __restrict__ x, const short* __restrict__ W1hT,
    const short* __restrict__ W1lT, const float* __restrict__ b1,
    const float* __restrict__ W2, const int* __restrict__ flagged,
    const int* __restrict__ nflag, float* __restrict__ partR) {
  __shared__ __align__(16) char smem[37888];
  __shared__ int toks[128];
  short* Ah = (short*)smem;
  short* Al = (short*)(smem + 8192);

  int nf = *nflag; if (nf > NTOK) nf = NTOK;
  const int m0 = blockIdx.x * 128;
  if (m0 >= nf) return;
  const int tid = threadIdx.x;
  if (tid < 128) {
    int s = m0 + tid;
    toks[tid] = flagged[s < nf ? s : nf - 1];
  }
  __syncthreads();

  const int lane = tid & 63, wave = tid >> 6;
  const int wr = wave >> 1, wc = wave & 1;
  const int fr = lane & 15, fg = lane >> 4;
  const int n0 = blockIdx.y * 128;
  const int by = blockIdx.y;

  const int off0 = wave * 1024 + lane * 16;
  const int off1 = off0 + 4096;
  const int r0 = off0 >> 6, c0 = (off0 & 63) >> 1;
  const int r1 = off1 >> 6, c1 = (off1 & 63) >> 1;
  const short* bh0p = W1hT + (size_t)(n0 + r0) * HD + c0;
  const short* bh1p = W1hT + (size_t)(n0 + r1) * HD + c1;
  const short* bl0p = W1lT + (size_t)(n0 + r0) * HD + c0;
  const short* bl1p = W1lT + (size_t)(n0 + r1) * HD + c1;
  char* ldsBh0 = smem + 16384 + wave * 1024;
  char* ldsBh1 = smem + 16384 + wave * 1024 + 4096;
  char* ldsBl0 = smem + 24576 + wave * 1024;
  char* ldsBl1 = smem + 24576 + wave * 1024 + 4096;
  const int ar = tid >> 1, ah2 = tid & 1;
  const float* aF = x + (size_t)toks[ar] * HD + ah2 * 16;

  f32x4 acc[4][4];
#pragma unroll
  for (int i = 0; i < 4; ++i)
#pragma unroll
    for (int j = 0; j < 4; ++j) acc[i][j] = (f32x4){0.f, 0.f, 0.f, 0.f};

  for (int k0 = 0; k0 < HD; k0 += 32) {
    gl16(ldsBh0, bh0p + k0);
    gl16(ldsBh1, bh1p + k0);
    gl16(ldsBl0, bl0p + k0);
    gl16(ldsBl1, bl1p + k0);
    f32x4 u0 = *(const f32x4*)(aF + k0);
    f32x4 u1 = *(const f32x4*)(aF + k0 + 4);
    f32x4 u2 = *(const f32x4*)(aF + k0 + 8);
    f32x4 u3 = *(const f32x4*)(aF + k0 + 12);
    short8 sh0, sh1, sl0, sl1;
#pragma unroll
    for (int q = 0; q < 4; ++q) {
      { float f = u0[q]; short h = f2bh(f); sh0[q]     = h; sl0[q]     = f2bh(f - bh2f(h)); }
      { float f = u1[q]; short h = f2bh(f); sh0[4 + q] = h; sl0[4 + q] = f2bh(f - bh2f(h)); }
      { float f = u2[q]; short h = f2bh(f); sh1[q]     = h; sl1[q]     = f2bh(f - bh2f(h)); }
      { float f = u3[q]; short h = f2bh(f); sh1[4 + q] = h; sl1[4 + q] = f2bh(f - bh2f(h)); }
    }
    *(short8*)(Ah + ar * 32 + ah2 * 16)     = sh0;
    *(short8*)(Ah + ar * 32 + ah2 * 16 + 8) = sh1;
    *(short8*)(Al + ar * 32 + ah2 * 16)     = sl0;
    *(short8*)(Al + ar * 32 + ah2 * 16 + 8) = sl1;
    __syncthreads();
    short8 af[4], alf[4], bf[4], blf[4];
#pragma unroll
    for (int i = 0; i < 4; ++i) {
      int row = (wr * 64 + i * 16 + fr) * 32 + fg * 8;
      af[i]  = *(const short8*)(Ah + row);
      alf[i] = *(const short8*)(Al + row);
      int rowb = (wc * 64 + i * 16 + fr) * 32 + fg * 8;
      bf[i]  = *(const short8*)((short*)(smem + 16384) + rowb);
      blf[i] = *(const short8*)((short*)(smem + 24576) + rowb);
    }
#pragma unroll
    for (int i = 0; i < 4; ++i)
#pragma unroll
      for (int j = 0; j < 4; ++j) {
        acc[i][j] = __builtin_amdgcn_mfma_f32_16x16x32_bf16(af[i],  bf[j],  acc[i][j], 0, 0, 0);
        acc[i][j] = __builtin_amdgcn_mfma_f32_16x16x32_bf16(af[i],  blf[j], acc[i][j], 0, 0, 0);
        acc[i][j] = __builtin_amdgcn_mfma_f32_16x16x32_bf16(alf[i], bf[j],  acc[i][j], 0, 0, 0);
      }
    __syncthreads();
  }

  float* hl64 = (float*)smem;            // [64][129]
  float* W2c  = (float*)(smem + 33024);  // [128][8]
  *(f32x4*)(W2c + tid * 4) = *(const f32x4*)(W2 + (size_t)n0 * NEXP + tid * 4);
  float b1j[4];
#pragma unroll
  for (int j = 0; j < 4; ++j) b1j[j] = b1[n0 + wc * 64 + j * 16 + fr];

  for (int p = 0; p < 2; ++p) {
    if (wr == p) {
#pragma unroll
      for (int i = 0; i < 4; ++i)
#pragma unroll
        for (int j = 0; j < 4; ++j) {
          int col = wc * 64 + j * 16 + fr;
#pragma unroll
          for (int q = 0; q < 4; ++q)
            hl64[(i * 16 + fg * 4 + q) * 129 + col] = fmaxf(acc[i][j][q] + b1j[j], 0.f);
        }
    }
    __syncthreads();
    if (tid < 128) {
      int r2 = tid & 63, eh = tid >> 6;
      const float* hrow = hl64 + r2 * 129;
      const float* wcp = W2c + eh * 4;
      float s0 = 0.f, s1 = 0.f, s2 = 0.f, s3 = 0.f;
      for (int f = 0; f < 128; ++f) {
        float hv = hrow[f];
        s0 += hv * wcp[f * 8 + 0];
        s1 += hv * wcp[f * 8 + 1];
        s2 += hv * wcp[f * 8 + 2];
        s3 += hv * wcp[f * 8 + 3];
      }
      float* pp = partR + (size_t)(m0 + p * 64 + r2) * 32 + by * 8 + eh * 4;
      pp[0] = s0; pp[1] = s1; pp[2] = s2; pp[3] = s3;
    }
    __syncthreads();
  }
}

// ---------------------------------------------------------------------------
__global__ __launch_bounds__(256) void k_combineR(
    const float* __restrict__ partR, const float* __restrict__ b2,
    const int* __restrict__ flagged, const int* __restrict__ nflag,
    int* __restrict__ sel, int* __restrict__ flagged2, int* __restrict__ nflag2) {
  int nf = *nflag; if (nf > NTOK) nf = NTOK;
  int s = blockIdx.x * 256 + threadIdx.x;
  if (s >= nf) return;
  int t = flagged[s];
  const float* p = partR + (size_t)s * 32;
  float lg[8];
#pragma unroll
  for (int e = 0; e < 8; ++e) lg[e] = p[e] + p[8 + e] + p[16 + e] + p[24 + e] + b2[e];
  int be = 0; float best = lg[0];
#pragma unroll
  for (int e = 1; e < 8; ++e) if (lg[e] > best) { best = lg[e]; be = e; }
  float second = -3.4e38f;
#pragma unroll
  for (int e = 0; e < 8; ++e) if (e != be && lg[e] > second) second = lg[e];
  sel[t] = be;
  if (best - second < TAU2) {
    int ix = atomicAdd(nflag2, 1);
    if (ix < NTOK) flagged2[ix] = t;
  }
}

// ---------------------------------------------------------------------------
__global__ __launch_bounds__(256) void k_recomputeB(
    const float* __restrict__ x, const float* __restrict__ W1,
    const float* __restrict__ b1, const float* __restrict__ W2,
    const float* __restrict__ b2, const int* __restrict__ flagged2,
    const int* __restrict__ nflag2, int* __restrict__ sel) {
  __shared__ float xs[1024];
  __shared__ double hs[512];
  __shared__ double red[8][32];
  __shared__ double lgd[8];
  int nf = *nflag2; if (nf > NTOK) nf = NTOK;
  const int tid = threadIdx.x;
  for (int ti = blockIdx.x; ti < nf; ti += gridDim.x) {
    int t = flagged2[ti];
    __syncthreads();
    for (int q = tid; q < 1024; q += 256) xs[q] = x[(size_t)t * HD + q];
    __syncthreads();
    int f0 = tid * 2;
    double a0 = 0.0, a1 = 0.0;
    for (int h = 0; h < 1024; h += 4) {
      float2 w0 = *(const float2*)(W1 + (size_t)(h + 0) * FD + f0);
      float2 w1 = *(const float2*)(W1 + (size_t)(h + 1) * FD + f0);
      float2 w2 = *(const float2*)(W1 + (size_t)(h + 2) * FD + f0);
      float2 w3 = *(const float2*)(W1 + (size_t)(h + 3) * FD + f0);
      double x0 = (double)xs[h], x1 = (double)xs[h + 1];
      double x2 = (double)xs[h + 2], x3 = (double)xs[h + 3];
      a0 += x0 * (double)w0.x; a1 += x0 * (double)w0.y;
      a0 += x1 * (double)w1.x; a1 += x1 * (double)w1.y;
      a0 += x2 * (double)w2.x; a1 += x2 * (double)w2.y;
      a0 += x3 * (double)w3.x; a1 += x3 * (double)w3.y;
    }
    a0 += (double)b1[f0]; a1 += (double)b1[f0 + 1];
    hs[f0]     = a0 > 0.0 ? a0 : 0.0;
    hs[f0 + 1] = a1 > 0.0 ? a1 : 0.0;
    __syncthreads();
    {
      int e = tid >> 5, c = tid & 31;
      int fb = c * 16;
      double s = 0.0;
#pragma unroll
      for (int ff = 0; ff < 16; ++ff)
        s += hs[fb + ff] * (double)W2[(size_t)(fb + ff) * 8 + e];
      red[e][c] = s;
    }
    __syncthreads();
    if (tid < 8) {
      double s = 0.0;
#pragma unroll
      for (int c = 0; c < 32; ++c) s += red[tid][c];
      lgd[tid] = s + (double)b2[tid];
    }
    __syncthreads();
    if (tid == 0) {
      int be = 0; double best = lgd[0];
#pragma unroll
      for (int e = 1; e < 8; ++e) if (lgd[e] > best) { best = lgd[e]; be = e; }
      sel[t] = be;
    }
    __syncthreads();
  }
}

// ---------------------------------------------------------------------------
__global__ __launch_bounds__(256) void k_compact(
    const int* __restrict__ sel, int* __restrict__ cnt, int* __restrict__ list) {
  __shared__ int wcnt[4][8];
  __shared__ int woff[4][8];
  __shared__ int bbase[8];
  const int tid = threadIdx.x, lane = tid & 63, wave = tid >> 6;
  const int t = blockIdx.x * 256 + tid;
  const int e = sel[t];
  const unsigned long long ltmask = (1ull << lane) - 1ull;
  int rank = 0;
#pragma unroll
  for (int e2 = 0; e2 < 8; ++e2) {
    unsigned long long m = __ballot(e == e2);
    if (e2 == e) rank = __popcll(m & ltmask);
    if (lane == 0) wcnt[wave][e2] = __popcll(m);
  }
  __syncthreads();
  if (tid < 8) {
    int s0 = wcnt[0][tid], s1 = wcnt[1][tid], s2 = wcnt[2][tid], s3 = wcnt[3][tid];
    woff[0][tid] = 0; woff[1][tid] = s0; woff[2][tid] = s0 + s1; woff[3][tid] = s0 + s1 + s2;
    bbase[tid] = atomicAdd(&cnt[tid], s0 + s1 + s2 + s3);
  }
  __syncthreads();
  list[(size_t)e * NTOK + bbase[e] + woff[wave][e] + rank] = t;
}

__global__ void k_build_desc(const int* __restrict__ cnt, int* __restrict__ desc,
                             int* __restrict__ ntl) {
  if (threadIdx.x == 0 && blockIdx.x == 0) {
    int n = 0;
    for (int e = 0; e < 8; ++e) {
      int m = (cnt[e] + 127) >> 7;
      for (int i = 0; i < m; ++i) desc[n++] = (e << 16) | i;
    }
    *ntl = n;
  }
}

// ---------------------------------------------------------------------------
// GEMM2: 128x128 tile, BK=32, 4 waves, gathered A rows. Counted-vmcnt dbuf
// pipeline (T4) + both-sides LDS swizzle (T2).
// ---------------------------------------------------------------------------
template <bool ABF>
__global__ __launch_bounds__(256) void k_gemm2(
    const short* __restrict__ xbf, const float* __restrict__ xf,
    const short* __restrict__ WexpT, const float* __restrict__ expert_b,
    const int* __restrict__ cnt, const int* __restrict__ list,
    const int* __restrict__ desc, const int* __restrict__ ntl,
    float* __restrict__ out) {
  __shared__ __align__(16) char smem[32768];
  __shared__ int toks[128];
  const int bx = (blockIdx.x % 8) * 33 + blockIdx.x / 8;  // T1 bijective, 264=8*33
  if (bx >= *ntl) return;
  int dsc = desc[bx];
  int e = dsc >> 16, mt = dsc & 0xffff;
  int ce = cnt[e];
  int mb = mt * 128;
  int rows = ce - mb; if (rows > 128) rows = 128;

  const int tid = threadIdx.x;
  if (tid < 128) {
    int idx = mb + tid;
    toks[tid] = list[(size_t)e * NTOK + (idx < ce ? idx : ce - 1)];
  }
  __syncthreads();

  const int lane = tid & 63, wave = tid >> 6;
  const int wr = wave >> 1, wc = wave & 1;
  const int fr = lane & 15, fg = lane >> 4;
  const int n0 = blockIdx.y * 128;

  const int r0 = wave * 16 + (lane >> 2);
  const int lsw = (((lane & 3) ^ ((lane >> 3) & 3)) << 3);
  const size_t ebase = (size_t)e << 20;
  const short* b0p = WexpT + ebase + (size_t)(n0 + r0) * HD + lsw;
  const short* b1p = WexpT + ebase + (size_t)(n0 + r0 + 64) * HD + lsw;

  const short* a0p = nullptr; const short* a1p = nullptr;
  const float* aF = nullptr;
  int ar = 0, ah = 0, p0e = 0, p1e = 0;
  if constexpr (ABF) {
    a0p = xbf + (size_t)toks[r0] * HD + lsw;
    a1p = xbf + (size_t)toks[r0 + 64] * HD + lsw;
  } else {
    ar = tid >> 1; ah = tid & 1;
    aF = xf + (size_t)toks[ar] * HD + ah * 16;
    int s = (ar >> 1) & 3;
    p0e = ((2 * ah) ^ s) << 3;
    p1e = p0e ^ 8;
  }

  f32x4 acc[4][4];
#pragma unroll
  for (int i = 0; i < 4; ++i)
#pragma unroll
    for (int j = 0; j < 4; ++j) acc[i][j] = (f32x4){0.f, 0.f, 0.f, 0.f};

  auto STAGE = [&](int kt, int b) {
    const int k0 = kt * 32;
    gl16(smem + 16384 + b * 8192 + wave * 1024, b0p + k0);
    gl16(smem + 16384 + b * 8192 + 4096 + wave * 1024, b1p + k0);
    if constexpr (ABF) {
      gl16(smem + b * 8192 + wave * 1024, a0p + k0);
      gl16(smem + b * 8192 + 4096 + wave * 1024, a1p + k0);
    } else {
      f32x4 u0 = *(const f32x4*)(aF + k0);
      f32x4 u1 = *(const f32x4*)(aF + k0 + 4);
      f32x4 u2 = *(const f32x4*)(aF + k0 + 8);
      f32x4 u3 = *(const f32x4*)(aF + k0 + 12);
      short8 s0, s1;
#pragma unroll
      for (int q = 0; q < 4; ++q) {
        s0[q] = f2bh(u0[q]); s0[4 + q] = f2bh(u1[q]);
        s1[q] = f2bh(u2[q]); s1[4 + q] = f2bh(u3[q]);
      }
      short* As = (short*)(smem + b * 8192);
      *(short8*)(As + ar * 32 + p0e) = s0;
      *(short8*)(As + ar * 32 + p1e) = s1;
    }
  };
  const int csw = (fr >> 1) & 3;
  auto COMPUTE = [&](int b) {
    const short* As = (const short*)(smem + b * 8192);
    const short* Bs = (const short*)(smem + 16384 + b * 8192);
    short8 af[4], bf4[4];
#pragma unroll
    for (int i = 0; i < 4; ++i) {
      af[i]  = *(const short8*)(As + (wr * 64 + i * 16 + fr) * 32 + ((fg ^ csw) << 3));
      bf4[i] = *(const short8*)(Bs + (wc * 64 + i * 16 + fr) * 32 + ((fg ^ csw) << 3));
    }
#pragma unroll
    for (int i = 0; i < 4; ++i)
#pragma unroll
      for (int j = 0; j < 4; ++j)
        acc[i][j] = __builtin_amdgcn_mfma_f32_16x16x32_bf16(af[i], bf4[j], acc[i][j], 0, 0, 0);
  };

  STAGE(0, 0);
  if constexpr (ABF) WAITBAR(0); else __syncthreads();
#pragma unroll 1
  for (int kt = 0; kt < 32; kt += 2) {
    STAGE(kt + 1, 1);
    if constexpr (ABF) WAITBAR(4); else __syncthreads();
    COMPUTE(0);
    if constexpr (ABF) BARO(); else __syncthreads();
    if (kt + 2 < 32) {
      STAGE(kt + 2, 0);
      if constexpr (ABF) WAITBAR(4); else __syncthreads();
    } else {
      if constexpr (ABF) WAITBAR(0); else __syncthreads();
    }
    COMPUTE(1);
    if constexpr (ABF) BARO(); else __syncthreads();
  }

  float ebv[4];
#pragma unroll
  for (int j = 0; j < 4; ++j) ebv[j] = expert_b[e * HD + n0 + wc * 64 + j * 16 + fr];
#pragma unroll
  for (int i = 0; i < 4; ++i)
#pragma unroll
    for (int j = 0; j < 4; ++j) {
      int col = n0 + wc * 64 + j * 16 + fr;
#pragma unroll
      for (int q = 0; q < 4; ++q) {
        int rr = wr * 64 + i * 16 + fg * 4 + q;
        if (rr < rows) out[(size_t)toks[rr] * HD + col] = acc[i][j][q] + ebv[j];
      }
    }
}

// ---------------------------------------------------------------------------
extern "C" void kernel_launch(void* const* d_in, const int* in_sizes, int n_in,
                              void* d_out, int out_size, void* d_ws, size_t ws_size,
                              hipStream_t stream) {
  const float* x  = (const float*)d_in[0];
  const float* W1 = (const float*)d_in[1];
  const float* b1 = (const float*)d_in[2];
  const float* W2 = (const float*)d_in[3];
  const float* b2 = (const float*)d_in[4];
  const float* eW = (const float*)d_in[5];
  const float* eb = (const float*)d_in[6];
  float* out = (float*)d_out;
  char* ws = (char*)d_ws;

  const size_t XBF_BYTES = (size_t)NTOK * HD * 2;  // 67,108,864
  size_t need_rest = 16777216ull + 1048576 + 4194304 + 131072 * 3 + 1048576 + 4096;
  bool big = ws_size >= XBF_BYTES + need_rest;

  size_t off = 0;
  short* xbf = nullptr;
  if (big) { xbf = (short*)ws; off += XBF_BYTES; }
  short* WexpT  = (short*)(ws + off); off += 16777216;
  short* W1T    = (short*)(ws + off); off += 1048576;
  float* part   = (float*)(ws + off); off += 4194304;   // also partR (tier-A)
  int* sel      = (int*)(ws + off); off += 131072;
  int* flagged  = (int*)(ws + off); off += 131072;
  int* flagged2 = (int*)(ws + off); off += 131072;
  int* list     = (int*)(ws + off); off += 1048576;     // also W1lT before compact
  int* cnt      = (int*)(ws + off); off += 32;
  int* nflag    = (int*)(ws + off); off += 4;
  int* ntl      = (int*)(ws + off); off += 4;
  int* nflag2   = (int*)(ws + off); off += 24;
  int* desc     = (int*)(ws + off); off += 1088;
  if (ws_size < off) return;

  short* W1lT = (short*)list;  // 1 MB, live until k_compact

  hipMemsetAsync(cnt, 0, 44, stream);  // cnt[8], nflag, ntl, nflag2

  dim3 b256(256);
  if (big) k_convert<<<dim3(16384), b256, 0, stream>>>(x, xbf);
  k_transpose_split<<<dim3(16, 32), b256, 0, stream>>>(W1, W1T, W1lT, 1024, 512);
  k_transpose<<<dim3(32, 32, 8), b256, 0, stream>>>(eW, WexpT, 1024, 1024);
  if (big)
    k_gemm1<true><<<dim3(256, 4), b256, 0, stream>>>(xbf, nullptr, W1T, b1, W2, part);
  else
    k_gemm1<false><<<dim3(256, 4), b256, 0, stream>>>(nullptr, x, W1T, b1, W2, part);
  k_combine<<<dim3(128), b256, 0, stream>>>(part, b2, sel, flagged, nflag);
  k_gemmR<<<dim3(256, 4), b256, 0, stream>>>(x, W1T, W1lT, b1, W2, flagged, nflag, part);
  k_combineR<<<dim3(128), b256, 0, stream>>>(part, b2, flagged, nflag, sel, flagged2, nflag2);
  k_recomputeB<<<dim3(128), b256, 0, stream>>>(x, W1, b1, W2, b2, flagged2, nflag2, sel);
  k_compact<<<dim3(128), b256, 0, stream>>>(sel, cnt, list);
  k_build_desc<<<dim3(1), dim3(64), 0, stream>>>(cnt, desc, ntl);
  if (big)
    k_gemm2<true><<<dim3(264, 8), b256, 0, stream>>>(xbf, nullptr, WexpT, eb, cnt, list, desc, ntl, out);
  else
    k_gemm2<false><<<dim3(264, 8), b256, 0, stream>>>(nullptr, x, WexpT, eb, cnt, list, desc, ntl, out);
}

// Round 8
// 352.802 us; speedup vs baseline: 1.0274x; 1.0261x over previous
//
#include <hip/hip_runtime.h>
#include <hip/hip_bf16.h>
#include <stdint.h>

#define NTOK 32768
#define HD 1024
#define FD 512
#define NEXP 8
#define TAU 0.05f
#define TAU2 4e-4f

typedef __attribute__((ext_vector_type(8))) short short8;
typedef __attribute__((ext_vector_type(4))) float f32x4;

__device__ __forceinline__ short f2bh(float f) {
  uint32_t u = __float_as_uint(f);
  return (short)((u + 0x7fffu + ((u >> 16) & 1u)) >> 16);
}
__device__ __forceinline__ float bh2f(short h) {
  return __uint_as_float(((uint32_t)(uint16_t)h) << 16);
}

__device__ __forceinline__ void gl16(void* lds, const void* g) {
  __builtin_amdgcn_global_load_lds(
      (const __attribute__((address_space(1))) void*)g,
      (__attribute__((address_space(3))) void*)lds, 16, 0, 0);
}

#define WAITBAR(N)                                              \
  do {                                                          \
    asm volatile("s_waitcnt vmcnt(" #N ")" ::: "memory");       \
    __builtin_amdgcn_s_barrier();                               \
    asm volatile("" ::: "memory");                              \
  } while (0)
#define BARO()                                                  \
  do {                                                          \
    asm volatile("" ::: "memory");                              \
    __builtin_amdgcn_s_barrier();                               \
    asm volatile("" ::: "memory");                              \
  } while (0)

// ---------------------------------------------------------------------------
__global__ __launch_bounds__(256) void k_convert(const float* __restrict__ x,
                                                 short* __restrict__ xbf) {
  size_t i = ((size_t)blockIdx.x * 256 + threadIdx.x) * 8;
  f32x4 v0 = *(const f32x4*)(x + i);
  f32x4 v1 = *(const f32x4*)(x + i + 4);
  short8 o;
#pragma unroll
  for (int q = 0; q < 4; ++q) { o[q] = f2bh(v0[q]); o[4 + q] = f2bh(v1[q]); }
  *(short8*)(xbf + i) = o;
}

// ---------------------------------------------------------------------------
__global__ __launch_bounds__(256) void k_transpose(
    const float* __restrict__ src, short* __restrict__ dst, int rows, int cols) {
  __shared__ float tile[32][33];
  size_t msz = (size_t)rows * cols;
  src += (size_t)blockIdx.z * msz;
  dst += (size_t)blockIdx.z * msz;
  int c0 = blockIdx.x * 32, r0 = blockIdx.y * 32;
  int tx = threadIdx.x & 31, ty = threadIdx.x >> 5;
#pragma unroll
  for (int i = 0; i < 32; i += 8)
    tile[ty + i][tx] = src[(size_t)(r0 + ty + i) * cols + c0 + tx];
  __syncthreads();
#pragma unroll
  for (int i = 0; i < 32; i += 8)
    dst[(size_t)(c0 + ty + i) * rows + r0 + tx] = f2bh(tile[tx][ty + i]);
}

// ---------------------------------------------------------------------------
__global__ __launch_bounds__(256) void k_transpose_split(
    const float* __restrict__ src, short* __restrict__ dstH,
    short* __restrict__ dstL, int rows, int cols) {
  __shared__ float tile[32][33];
  int c0 = blockIdx.x * 32, r0 = blockIdx.y * 32;
  int tx = threadIdx.x & 31, ty = threadIdx.x >> 5;
#pragma unroll
  for (int i = 0; i < 32; i += 8)
    tile[ty + i][tx] = src[(size_t)(r0 + ty + i) * cols + c0 + tx];
  __syncthreads();
#pragma unroll
  for (int i = 0; i < 32; i += 8) {
    float v = tile[tx][ty + i];
    short h = f2bh(v);
    size_t di = (size_t)(c0 + ty + i) * rows + r0 + tx;
    dstH[di] = h;
    dstL[di] = f2bh(v - bh2f(h));
  }
}

// ---------------------------------------------------------------------------
// GEMM1: 128x128 tile, BK=32, 4 waves. 3-buffer depth-2 counted-vmcnt
// pipeline (T4) + both-sides LDS swizzle (T2). MFMA logits epilogue.
// ---------------------------------------------------------------------------
template <bool ABF>
__global__ __launch_bounds__(256) void k_gemm1(
    const short* __restrict__ xbf, const float* __restrict__ xf,
    const short* __restrict__ W1T, const float* __restrict__ b1,
    const float* __restrict__ W2, float* __restrict__ part) {
  __shared__ __align__(16) char smem[49152];
  // A bufs: [0,24K) in 8K steps; B bufs: [24K,48K)

  const int tid = threadIdx.x;
  const int lane = tid & 63, wave = tid >> 6;
  const int wr = wave >> 1, wc = wave & 1;
  const int fr = lane & 15, fg = lane >> 4;
  const int bx = ((blockIdx.x & 7) << 5) | (blockIdx.x >> 3);  // T1, 256=8*32
  const int m0 = bx * 128, n0 = blockIdx.y * 128;
  const int by = blockIdx.y;

  // swizzled staging (T2): slot = r*4 + (c ^ ((r>>1)&3)), LDS linear
  const int r0 = wave * 16 + (lane >> 2);
  const int lsw = (((lane & 3) ^ ((lane >> 3) & 3)) << 3);
  const short* b0p = W1T + (size_t)(n0 + r0) * HD + lsw;
  const short* b1p = W1T + (size_t)(n0 + r0 + 64) * HD + lsw;

  const short* a0p = nullptr; const short* a1p = nullptr;
  const float* aF = nullptr;
  int ar = 0, ah = 0, p0e = 0, p1e = 0;
  if constexpr (ABF) {
    a0p = xbf + (size_t)(m0 + r0) * HD + lsw;
    a1p = xbf + (size_t)(m0 + r0 + 64) * HD + lsw;
  } else {
    ar = tid >> 1; ah = tid & 1;
    aF = xf + (size_t)(m0 + ar) * HD + ah * 16;
    int s = (ar >> 1) & 3;
    p0e = ((2 * ah) ^ s) << 3;
    p1e = p0e ^ 8;
  }

  f32x4 acc[4][4];
#pragma unroll
  for (int i = 0; i < 4; ++i)
#pragma unroll
    for (int j = 0; j < 4; ++j) acc[i][j] = (f32x4){0.f, 0.f, 0.f, 0.f};

  const int csw = (fr >> 1) & 3;
  auto COMPUTE = [&](int b) {
    const short* As = (const short*)(smem + b * 8192);
    const short* Bs = (const short*)(smem + 24576 + b * 8192);
    short8 af[4], bf4[4];
#pragma unroll
    for (int i = 0; i < 4; ++i) {
      af[i]  = *(const short8*)(As + (wr * 64 + i * 16 + fr) * 32 + ((fg ^ csw) << 3));
      bf4[i] = *(const short8*)(Bs + (wc * 64 + i * 16 + fr) * 32 + ((fg ^ csw) << 3));
    }
#pragma unroll
    for (int i = 0; i < 4; ++i)
#pragma unroll
      for (int j = 0; j < 4; ++j)
        acc[i][j] = __builtin_amdgcn_mfma_f32_16x16x32_bf16(af[i], bf4[j], acc[i][j], 0, 0, 0);
  };

  if constexpr (ABF) {
    auto STAGE = [&](int kt, int b) {
      const int k0 = kt * 32;
      gl16(smem + 24576 + b * 8192 + wave * 1024, b0p + k0);
      gl16(smem + 24576 + b * 8192 + 4096 + wave * 1024, b1p + k0);
      gl16(smem + b * 8192 + wave * 1024, a0p + k0);
      gl16(smem + b * 8192 + 4096 + wave * 1024, a1p + k0);
    };
    STAGE(0, 0); STAGE(1, 1); STAGE(2, 2);
#pragma unroll 1
    for (int t = 0; t < 32; ++t) {
      if (t < 30) WAITBAR(8); else if (t == 30) WAITBAR(4); else WAITBAR(0);
      COMPUTE(t % 3);
      BARO();
      if (t < 29) STAGE(t + 3, t % 3);
    }
  } else {
    auto STAGEF = [&](int kt) {
      const int k0 = kt * 32;
      gl16(smem + 24576 + wave * 1024, b0p + k0);
      gl16(smem + 24576 + 4096 + wave * 1024, b1p + k0);
      f32x4 u0 = *(const f32x4*)(aF + k0);
      f32x4 u1 = *(const f32x4*)(aF + k0 + 4);
      f32x4 u2 = *(const f32x4*)(aF + k0 + 8);
      f32x4 u3 = *(const f32x4*)(aF + k0 + 12);
      short8 s0, s1;
#pragma unroll
      for (int q = 0; q < 4; ++q) {
        s0[q] = f2bh(u0[q]); s0[4 + q] = f2bh(u1[q]);
        s1[q] = f2bh(u2[q]); s1[4 + q] = f2bh(u3[q]);
      }
      short* As = (short*)smem;
      *(short8*)(As + ar * 32 + p0e) = s0;
      *(short8*)(As + ar * 32 + p1e) = s1;
    };
#pragma unroll 1
    for (int kt = 0; kt < 32; ++kt) {
      STAGEF(kt);
      __syncthreads();
      COMPUTE(0);
      __syncthreads();
    }
  }

  // Epilogue: relu(acc+b1) -> hbf [128][136] bf16; logits via MFMA vs
  // W2b [16][136] (cols 8..15 zero).
  short* hbf = (short*)smem;            // 34816 B
  short* W2b = (short*)(smem + 34816);  // 4352 B
  float b1j[4];
#pragma unroll
  for (int j = 0; j < 4; ++j) b1j[j] = b1[n0 + wc * 64 + j * 16 + fr];
  for (int q = tid; q < 2048; q += 256) {
    int col = q >> 7, k = q & 127;
    W2b[col * 136 + k] = (col < 8) ? f2bh(W2[(size_t)(n0 + k) * 8 + col]) : (short)0;
  }
#pragma unroll
  for (int i = 0; i < 4; ++i)
#pragma unroll
    for (int j = 0; j < 4; ++j) {
      int col = wc * 64 + j * 16 + fr;
#pragma unroll
      for (int q = 0; q < 4; ++q)
        hbf[(wr * 64 + i * 16 + fg * 4 + q) * 136 + col] =
            f2bh(fmaxf(acc[i][j][q] + b1j[j], 0.f));
    }
  __syncthreads();
#pragma unroll
  for (int rg = 0; rg < 2; ++rg) {
    int row16 = wave * 32 + rg * 16;
    f32x4 accl = (f32x4){0.f, 0.f, 0.f, 0.f};
#pragma unroll
    for (int kk = 0; kk < 4; ++kk) {
      short8 a = *(const short8*)(hbf + (row16 + fr) * 136 + kk * 32 + fg * 8);
      short8 b = *(const short8*)(W2b + fr * 136 + kk * 32 + fg * 8);
      accl = __builtin_amdgcn_mfma_f32_16x16x32_bf16(a, b, accl, 0, 0, 0);
    }
    if (fr < 8) {
      float* pp = part + (size_t)(m0 + row16 + fg * 4) * 32 + by * 8 + fr;
#pragma unroll
      for (int q = 0; q < 4; ++q) pp[(size_t)q * 32] = accl[q];
    }
  }
}

// ---------------------------------------------------------------------------
__global__ __launch_bounds__(256) void k_combine(
    const float* __restrict__ part, const float* __restrict__ b2,
    int* __restrict__ sel, int* __restrict__ flagged, int* __restrict__ nflag) {
  int t = blockIdx.x * 256 + threadIdx.x;
  const float* p = part + (size_t)t * 32;
  float lg[8];
#pragma unroll
  for (int e = 0; e < 8; ++e) lg[e] = p[e] + p[8 + e] + p[16 + e] + p[24 + e] + b2[e];
  int be = 0; float best = lg[0];
#pragma unroll
  for (int e = 1; e < 8; ++e) if (lg[e] > best) { best = lg[e]; be = e; }
  float second = -3.4e38f;
#pragma unroll
  for (int e = 0; e < 8; ++e) if (e != be && lg[e] > second) second = lg[e];
  sel[t] = be;
  if (best - second < TAU) {
    int ix = atomicAdd(nflag, 1);
    if (ix < NTOK) flagged[ix] = t;
  }
}

// ---------------------------------------------------------------------------
// Tier-A: bf16x3 re-GEMM of flagged tokens (unchanged).
// ---------------------------------------------------------------------------
__global__ __launch_bounds__(256) void k_gemmR(
    const float* __restrict__ x, const short* __restrict__ W1hT,
    const short* __restrict__ W1lT, const float* __restrict__ b1,
    const float* __restrict__ W2, const int* __restrict__ flagged,
    const int* __restrict__ nflag, float* __restrict__ partR) {
  __shared__ __align__(16) char smem[37888];
  __shared__ int toks[128];
  short* Ah = (short*)smem;
  short* Al = (short*)(smem + 8192);

  int nf = *nflag; if (nf > NTOK) nf = NTOK;
  const int m0 = blockIdx.x * 128;
  if (m0 >= nf) return;
  const int tid = threadIdx.x;
  if (tid < 128) {
    int s = m0 + tid;
    toks[tid] = flagged[s < nf ? s : nf - 1];
  }
  __syncthreads();

  const int lane = tid & 63, wave = tid >> 6;
  const int wr = wave >> 1, wc = wave & 1;
  const int fr = lane & 15, fg = lane >> 4;
  const int n0 = blockIdx.y * 128;
  const int by = blockIdx.y;

  const int off0 = wave * 1024 + lane * 16;
  const int off1 = off0 + 4096;
  const int r0 = off0 >> 6, c0 = (off0 & 63) >> 1;
  const int r1 = off1 >> 6, c1 = (off1 & 63) >> 1;
  const short* bh0p = W1hT + (size_t)(n0 + r0) * HD + c0;
  const short* bh1p = W1hT + (size_t)(n0 + r1) * HD + c1;
  const short* bl0p = W1lT + (size_t)(n0 + r0) * HD + c0;
  const short* bl1p = W1lT + (size_t)(n0 + r1) * HD + c1;
  char* ldsBh0 = smem + 16384 + wave * 1024;
  char* ldsBh1 = smem + 16384 + wave * 1024 + 4096;
  char* ldsBl0 = smem + 24576 + wave * 1024;
  char* ldsBl1 = smem + 24576 + wave * 1024 + 4096;
  const int ar = tid >> 1, ah2 = tid & 1;
  const float* aF = x + (size_t)toks[ar] * HD + ah2 * 16;

  f32x4 acc[4][4];
#pragma unroll
  for (int i = 0; i < 4; ++i)
#pragma unroll
    for (int j = 0; j < 4; ++j) acc[i][j] = (f32x4){0.f, 0.f, 0.f, 0.f};

  for (int k0 = 0; k0 < HD; k0 += 32) {
    gl16(ldsBh0, bh0p + k0);
    gl16(ldsBh1, bh1p + k0);
    gl16(ldsBl0, bl0p + k0);
    gl16(ldsBl1, bl1p + k0);
    f32x4 u0 = *(const f32x4*)(aF + k0);
    f32x4 u1 = *(const f32x4*)(aF + k0 + 4);
    f32x4 u2 = *(const f32x4*)(aF + k0 + 8);
    f32x4 u3 = *(const f32x4*)(aF + k0 + 12);
    short8 sh0, sh1, sl0, sl1;
#pragma unroll
    for (int q = 0; q < 4; ++q) {
      { float f = u0[q]; short h = f2bh(f); sh0[q]     = h; sl0[q]     = f2bh(f - bh2f(h)); }
      { float f = u1[q]; short h = f2bh(f); sh0[4 + q] = h; sl0[4 + q] = f2bh(f - bh2f(h)); }
      { float f = u2[q]; short h = f2bh(f); sh1[q]     = h; sl1[q]     = f2bh(f - bh2f(h)); }
      { float f = u3[q]; short h = f2bh(f); sh1[4 + q] = h; sl1[4 + q] = f2bh(f - bh2f(h)); }
    }
    *(short8*)(Ah + ar * 32 + ah2 * 16)     = sh0;
    *(short8*)(Ah + ar * 32 + ah2 * 16 + 8) = sh1;
    *(short8*)(Al + ar * 32 + ah2 * 16)     = sl0;
    *(short8*)(Al + ar * 32 + ah2 * 16 + 8) = sl1;
    __syncthreads();
    short8 af[4], alf[4], bf[4], blf[4];
#pragma unroll
    for (int i = 0; i < 4; ++i) {
      int row = (wr * 64 + i * 16 + fr) * 32 + fg * 8;
      af[i]  = *(const short8*)(Ah + row);
      alf[i] = *(const short8*)(Al + row);
      int rowb = (wc * 64 + i * 16 + fr) * 32 + fg * 8;
      bf[i]  = *(const short8*)((short*)(smem + 16384) + rowb);
      blf[i] = *(const short8*)((short*)(smem + 24576) + rowb);
    }
#pragma unroll
    for (int i = 0; i < 4; ++i)
#pragma unroll
      for (int j = 0; j < 4; ++j) {
        acc[i][j] = __builtin_amdgcn_mfma_f32_16x16x32_bf16(af[i],  bf[j],  acc[i][j], 0, 0, 0);
        acc[i][j] = __builtin_amdgcn_mfma_f32_16x16x32_bf16(af[i],  blf[j], acc[i][j], 0, 0, 0);
        acc[i][j] = __builtin_amdgcn_mfma_f32_16x16x32_bf16(alf[i], bf[j],  acc[i][j], 0, 0, 0);
      }
    __syncthreads();
  }

  float* hl64 = (float*)smem;            // [64][129]
  float* W2c  = (float*)(smem + 33024);  // [128][8]
  *(f32x4*)(W2c + tid * 4) = *(const f32x4*)(W2 + (size_t)n0 * NEXP + tid * 4);
  float b1j[4];
#pragma unroll
  for (int j = 0; j < 4; ++j) b1j[j] = b1[n0 + wc * 64 + j * 16 + fr];

  for (int p = 0; p < 2; ++p) {
    if (wr == p) {
#pragma unroll
      for (int i = 0; i < 4; ++i)
#pragma unroll
        for (int j = 0; j < 4; ++j) {
          int col = wc * 64 + j * 16 + fr;
#pragma unroll
          for (int q = 0; q < 4; ++q)
            hl64[(i * 16 + fg * 4 + q) * 129 + col] = fmaxf(acc[i][j][q] + b1j[j], 0.f);
        }
    }
    __syncthreads();
    if (tid < 128) {
      int r2 = tid & 63, eh = tid >> 6;
      const float* hrow = hl64 + r2 * 129;
      const float* wcp = W2c + eh * 4;
      float s0 = 0.f, s1 = 0.f, s2 = 0.f, s3 = 0.f;
      for (int f = 0; f < 128; ++f) {
        float hv = hrow[f];
        s0 += hv * wcp[f * 8 + 0];
        s1 += hv * wcp[f * 8 + 1];
        s2 += hv * wcp[f * 8 + 2];
        s3 += hv * wcp[f * 8 + 3];
      }
      float* pp = partR + (size_t)(m0 + p * 64 + r2) * 32 + by * 8 + eh * 4;
      pp[0] = s0; pp[1] = s1; pp[2] = s2; pp[3] = s3;
    }
    __syncthreads();
  }
}

// ---------------------------------------------------------------------------
__global__ __launch_bounds__(256) void k_combineR(
    const float* __restrict__ partR, const float* __restrict__ b2,
    const int* __restrict__ flagged, const int* __restrict__ nflag,
    int* __restrict__ sel, int* __restrict__ flagged2, int* __restrict__ nflag2) {
  int nf = *nflag; if (nf > NTOK) nf = NTOK;
  int s = blockIdx.x * 256 + threadIdx.x;
  if (s >= nf) return;
  int t = flagged[s];
  const float* p = partR + (size_t)s * 32;
  float lg[8];
#pragma unroll
  for (int e = 0; e < 8; ++e) lg[e] = p[e] + p[8 + e] + p[16 + e] + p[24 + e] + b2[e];
  int be = 0; float best = lg[0];
#pragma unroll
  for (int e = 1; e < 8; ++e) if (lg[e] > best) { best = lg[e]; be = e; }
  float second = -3.4e38f;
#pragma unroll
  for (int e = 0; e < 8; ++e) if (e != be && lg[e] > second) second = lg[e];
  sel[t] = be;
  if (best - second < TAU2) {
    int ix = atomicAdd(nflag2, 1);
    if (ix < NTOK) flagged2[ix] = t;
  }
}

// ---------------------------------------------------------------------------
__global__ __launch_bounds__(256) void k_recomputeB(
    const float* __restrict__ x, const float* __restrict__ W1,
    const float* __restrict__ b1, const float* __restrict__ W2,
    const float* __restrict__ b2, const int* __restrict__ flagged2,
    const int* __restrict__ nflag2, int* __restrict__ sel) {
  __shared__ float xs[1024];
  __shared__ double hs[512];
  __shared__ double red[8][32];
  __shared__ double lgd[8];
  int nf = *nflag2; if (nf > NTOK) nf = NTOK;
  const int tid = threadIdx.x;
  for (int ti = blockIdx.x; ti < nf; ti += gridDim.x) {
    int t = flagged2[ti];
    __syncthreads();
    for (int q = tid; q < 1024; q += 256) xs[q] = x[(size_t)t * HD + q];
    __syncthreads();
    int f0 = tid * 2;
    double a0 = 0.0, a1 = 0.0;
    for (int h = 0; h < 1024; h += 4) {
      float2 w0 = *(const float2*)(W1 + (size_t)(h + 0) * FD + f0);
      float2 w1 = *(const float2*)(W1 + (size_t)(h + 1) * FD + f0);
      float2 w2 = *(const float2*)(W1 + (size_t)(h + 2) * FD + f0);
      float2 w3 = *(const float2*)(W1 + (size_t)(h + 3) * FD + f0);
      double x0 = (double)xs[h], x1 = (double)xs[h + 1];
      double x2 = (double)xs[h + 2], x3 = (double)xs[h + 3];
      a0 += x0 * (double)w0.x; a1 += x0 * (double)w0.y;
      a0 += x1 * (double)w1.x; a1 += x1 * (double)w1.y;
      a0 += x2 * (double)w2.x; a1 += x2 * (double)w2.y;
      a0 += x3 * (double)w3.x; a1 += x3 * (double)w3.y;
    }
    a0 += (double)b1[f0]; a1 += (double)b1[f0 + 1];
    hs[f0]     = a0 > 0.0 ? a0 : 0.0;
    hs[f0 + 1] = a1 > 0.0 ? a1 : 0.0;
    __syncthreads();
    {
      int e = tid >> 5, c = tid & 31;
      int fb = c * 16;
      double s = 0.0;
#pragma unroll
      for (int ff = 0; ff < 16; ++ff)
        s += hs[fb + ff] * (double)W2[(size_t)(fb + ff) * 8 + e];
      red[e][c] = s;
    }
    __syncthreads();
    if (tid < 8) {
      double s = 0.0;
#pragma unroll
      for (int c = 0; c < 32; ++c) s += red[tid][c];
      lgd[tid] = s + (double)b2[tid];
    }
    __syncthreads();
    if (tid == 0) {
      int be = 0; double best = lgd[0];
#pragma unroll
      for (int e = 1; e < 8; ++e) if (lgd[e] > best) { best = lgd[e]; be = e; }
      sel[t] = be;
    }
    __syncthreads();
  }
}

// ---------------------------------------------------------------------------
__global__ __launch_bounds__(256) void k_compact(
    const int* __restrict__ sel, int* __restrict__ cnt, int* __restrict__ list) {
  __shared__ int wcnt[4][8];
  __shared__ int woff[4][8];
  __shared__ int bbase[8];
  const int tid = threadIdx.x, lane = tid & 63, wave = tid >> 6;
  const int t = blockIdx.x * 256 + tid;
  const int e = sel[t];
  const unsigned long long ltmask = (1ull << lane) - 1ull;
  int rank = 0;
#pragma unroll
  for (int e2 = 0; e2 < 8; ++e2) {
    unsigned long long m = __ballot(e == e2);
    if (e2 == e) rank = __popcll(m & ltmask);
    if (lane == 0) wcnt[wave][e2] = __popcll(m);
  }
  __syncthreads();
  if (tid < 8) {
    int s0 = wcnt[0][tid], s1 = wcnt[1][tid], s2 = wcnt[2][tid], s3 = wcnt[3][tid];
    woff[0][tid] = 0; woff[1][tid] = s0; woff[2][tid] = s0 + s1; woff[3][tid] = s0 + s1 + s2;
    bbase[tid] = atomicAdd(&cnt[tid], s0 + s1 + s2 + s3);
  }
  __syncthreads();
  list[(size_t)e * NTOK + bbase[e] + woff[wave][e] + rank] = t;
}

__global__ void k_build_desc(const int* __restrict__ cnt, int* __restrict__ desc,
                             int* __restrict__ ntl) {
  if (threadIdx.x == 0 && blockIdx.x == 0) {
    int n = 0;
    for (int e = 0; e < 8; ++e) {
      int m = (cnt[e] + 127) >> 7;
      for (int i = 0; i < m; ++i) desc[n++] = (e << 16) | i;
    }
    *ntl = n;
  }
}

// ---------------------------------------------------------------------------
// GEMM2: 128x128 tile, BK=32, 4 waves, gathered A rows. 3-buffer depth-2
// counted-vmcnt pipeline (T4) + both-sides LDS swizzle (T2).
// ---------------------------------------------------------------------------
template <bool ABF>
__global__ __launch_bounds__(256) void k_gemm2(
    const short* __restrict__ xbf, const float* __restrict__ xf,
    const short* __restrict__ WexpT, const float* __restrict__ expert_b,
    const int* __restrict__ cnt, const int* __restrict__ list,
    const int* __restrict__ desc, const int* __restrict__ ntl,
    float* __restrict__ out) {
  __shared__ __align__(16) char smem[49152];
  __shared__ int toks[128];
  const int bx = (blockIdx.x % 8) * 33 + blockIdx.x / 8;  // T1 bijective, 264=8*33
  if (bx >= *ntl) return;
  int dsc = desc[bx];
  int e = dsc >> 16, mt = dsc & 0xffff;
  int ce = cnt[e];
  int mb = mt * 128;
  int rows = ce - mb; if (rows > 128) rows = 128;

  const int tid = threadIdx.x;
  if (tid < 128) {
    int idx = mb + tid;
    toks[tid] = list[(size_t)e * NTOK + (idx < ce ? idx : ce - 1)];
  }
  __syncthreads();

  const int lane = tid & 63, wave = tid >> 6;
  const int wr = wave >> 1, wc = wave & 1;
  const int fr = lane & 15, fg = lane >> 4;
  const int n0 = blockIdx.y * 128;

  const int r0 = wave * 16 + (lane >> 2);
  const int lsw = (((lane & 3) ^ ((lane >> 3) & 3)) << 3);
  const size_t ebase = (size_t)e << 20;
  const short* b0p = WexpT + ebase + (size_t)(n0 + r0) * HD + lsw;
  const short* b1p = WexpT + ebase + (size_t)(n0 + r0 + 64) * HD + lsw;

  const short* a0p = nullptr; const short* a1p = nullptr;
  const float* aF = nullptr;
  int ar = 0, ah = 0, p0e = 0, p1e = 0;
  if constexpr (ABF) {
    a0p = xbf + (size_t)toks[r0] * HD + lsw;
    a1p = xbf + (size_t)toks[r0 + 64] * HD + lsw;
  } else {
    ar = tid >> 1; ah = tid & 1;
    aF = xf + (size_t)toks[ar] * HD + ah * 16;
    int s = (ar >> 1) & 3;
    p0e = ((2 * ah) ^ s) << 3;
    p1e = p0e ^ 8;
  }

  f32x4 acc[4][4];
#pragma unroll
  for (int i = 0; i < 4; ++i)
#pragma unroll
    for (int j = 0; j < 4; ++j) acc[i][j] = (f32x4){0.f, 0.f, 0.f, 0.f};

  const int csw = (fr >> 1) & 3;
  auto COMPUTE = [&](int b) {
    const short* As = (const short*)(smem + b * 8192);
    const short* Bs = (const short*)(smem + 24576 + b * 8192);
    short8 af[4], bf4[4];
#pragma unroll
    for (int i = 0; i < 4; ++i) {
      af[i]  = *(const short8*)(As + (wr * 64 + i * 16 + fr) * 32 + ((fg ^ csw) << 3));
      bf4[i] = *(const short8*)(Bs + (wc * 64 + i * 16 + fr) * 32 + ((fg ^ csw) << 3));
    }
#pragma unroll
    for (int i = 0; i < 4; ++i)
#pragma unroll
      for (int j = 0; j < 4; ++j)
        acc[i][j] = __builtin_amdgcn_mfma_f32_16x16x32_bf16(af[i], bf4[j], acc[i][j], 0, 0, 0);
  };

  if constexpr (ABF) {
    auto STAGE = [&](int kt, int b) {
      const int k0 = kt * 32;
      gl16(smem + 24576 + b * 8192 + wave * 1024, b0p + k0);
      gl16(smem + 24576 + b * 8192 + 4096 + wave * 1024, b1p + k0);
      gl16(smem + b * 8192 + wave * 1024, a0p + k0);
      gl16(smem + b * 8192 + 4096 + wave * 1024, a1p + k0);
    };
    STAGE(0, 0); STAGE(1, 1); STAGE(2, 2);
#pragma unroll 1
    for (int t = 0; t < 32; ++t) {
      if (t < 30) WAITBAR(8); else if (t == 30) WAITBAR(4); else WAITBAR(0);
      COMPUTE(t % 3);
      BARO();
      if (t < 29) STAGE(t + 3, t % 3);
    }
  } else {
    auto STAGEF = [&](int kt) {
      const int k0 = kt * 32;
      gl16(smem + 24576 + wave * 1024, b0p + k0);
      gl16(smem + 24576 + 4096 + wave * 1024, b1p + k0);
      f32x4 u0 = *(const f32x4*)(aF + k0);
      f32x4 u1 = *(const f32x4*)(aF + k0 + 4);
      f32x4 u2 = *(const f32x4*)(aF + k0 + 8);
      f32x4 u3 = *(const f32x4*)(aF + k0 + 12);
      short8 s0, s1;
#pragma unroll
      for (int q = 0; q < 4; ++q) {
        s0[q] = f2bh(u0[q]); s0[4 + q] = f2bh(u1[q]);
        s1[q] = f2bh(u2[q]); s1[4 + q] = f2bh(u3[q]);
      }
      short* As = (short*)smem;
      *(short8*)(As + ar * 32 + p0e) = s0;
      *(short8*)(As + ar * 32 + p1e) = s1;
    };
#pragma unroll 1
    for (int kt = 0; kt < 32; ++kt) {
      STAGEF(kt);
      __syncthreads();
      COMPUTE(0);
      __syncthreads();
    }
  }

  float ebv[4];
#pragma unroll
  for (int j = 0; j < 4; ++j) ebv[j] = expert_b[e * HD + n0 + wc * 64 + j * 16 + fr];
#pragma unroll
  for (int i = 0; i < 4; ++i)
#pragma unroll
    for (int j = 0; j < 4; ++j) {
      int col = n0 + wc * 64 + j * 16 + fr;
#pragma unroll
      for (int q = 0; q < 4; ++q) {
        int rr = wr * 64 + i * 16 + fg * 4 + q;
        if (rr < rows) out[(size_t)toks[rr] * HD + col] = acc[i][j][q] + ebv[j];
      }
    }
}

// ---------------------------------------------------------------------------
extern "C" void kernel_launch(void* const* d_in, const int* in_sizes, int n_in,
                              void* d_out, int out_size, void* d_ws, size_t ws_size,
                              hipStream_t stream) {
  const float* x  = (const float*)d_in[0];
  const float* W1 = (const float*)d_in[1];
  const float* b1 = (const float*)d_in[2];
  const float* W2 = (const float*)d_in[3];
  const float* b2 = (const float*)d_in[4];
  const float* eW = (const float*)d_in[5];
  const float* eb = (const float*)d_in[6];
  float* out = (float*)d_out;
  char* ws = (char*)d_ws;

  const size_t XBF_BYTES = (size_t)NTOK * HD * 2;  // 67,108,864
  size_t need_rest = 16777216ull + 1048576 + 4194304 + 131072 * 3 + 1048576 + 4096;
  bool big = ws_size >= XBF_BYTES + need_rest;

  size_t off = 0;
  short* xbf = nullptr;
  if (big) { xbf = (short*)ws; off += XBF_BYTES; }
  short* WexpT  = (short*)(ws + off); off += 16777216;
  short* W1T    = (short*)(ws + off); off += 1048576;
  float* part   = (float*)(ws + off); off += 4194304;   // also partR (tier-A)
  int* sel      = (int*)(ws + off); off += 131072;
  int* flagged  = (int*)(ws + off); off += 131072;
  int* flagged2 = (int*)(ws + off); off += 131072;
  int* list     = (int*)(ws + off); off += 1048576;     // also W1lT before compact
  int* cnt      = (int*)(ws + off); off += 32;
  int* nflag    = (int*)(ws + off); off += 4;
  int* ntl      = (int*)(ws + off); off += 4;
  int* nflag2   = (int*)(ws + off); off += 24;
  int* desc     = (int*)(ws + off); off += 1088;
  if (ws_size < off) return;

  short* W1lT = (short*)list;  // 1 MB, live until k_compact

  hipMemsetAsync(cnt, 0, 44, stream);  // cnt[8], nflag, ntl, nflag2

  dim3 b256(256);
  if (big) k_convert<<<dim3(16384), b256, 0, stream>>>(x, xbf);
  k_transpose_split<<<dim3(16, 32), b256, 0, stream>>>(W1, W1T, W1lT, 1024, 512);
  k_transpose<<<dim3(32, 32, 8), b256, 0, stream>>>(eW, WexpT, 1024, 1024);
  if (big)
    k_gemm1<true><<<dim3(256, 4), b256, 0, stream>>>(xbf, nullptr, W1T, b1, W2, part);
  else
    k_gemm1<false><<<dim3(256, 4), b256, 0, stream>>>(nullptr, x, W1T, b1, W2, part);
  k_combine<<<dim3(128), b256, 0, stream>>>(part, b2, sel, flagged, nflag);
  k_gemmR<<<dim3(256, 4), b256, 0, stream>>>(x, W1T, W1lT, b1, W2, flagged, nflag, part);
  k_combineR<<<dim3(128), b256, 0, stream>>>(part, b2, flagged, nflag, sel, flagged2, nflag2);
  k_recomputeB<<<dim3(128), b256, 0, stream>>>(x, W1, b1, W2, b2, flagged2, nflag2, sel);
  k_compact<<<dim3(128), b256, 0, stream>>>(sel, cnt, list);
  k_build_desc<<<dim3(1), dim3(64), 0, stream>>>(cnt, desc, ntl);
  if (big)
    k_gemm2<true><<<dim3(264, 8), b256, 0, stream>>>(xbf, nullptr, WexpT, eb, cnt, list, desc, ntl, out);
  else
    k_gemm2<false><<<dim3(264, 8), b256, 0, stream>>>(nullptr, x, WexpT, eb, cnt, list, desc, ntl, out);
}